// Round 16
// baseline (202.690 us; speedup 1.0000x reference)
//
#include <hip/hip_runtime.h>

typedef unsigned short u16;
typedef __attribute__((ext_vector_type(8))) short short8;
typedef __attribute__((ext_vector_type(4))) short s16x4;
typedef __attribute__((ext_vector_type(4))) float f32x4;
typedef __attribute__((ext_vector_type(4))) u16 u16x4;

#define GPTR(p) ((const __attribute__((address_space(1))) void*)(p))
#define LPTR(p) ((__attribute__((address_space(3))) void*)(p))

#if __has_builtin(__builtin_amdgcn_mfma_f32_16x16x16bf16_1k)
#define MFMA16x16(a, b, c) __builtin_amdgcn_mfma_f32_16x16x16bf16_1k(a, b, c, 0, 0, 0)
#elif __has_builtin(__builtin_amdgcn_mfma_f32_16x16x16_bf16)
#define MFMA16x16(a, b, c) __builtin_amdgcn_mfma_f32_16x16x16_bf16(a, b, c, 0, 0, 0)
#else
__host__ __device__ static inline f32x4 MFMA16x16_host_stub(s16x4, s16x4, f32x4 c) { return c; }
#define MFMA16x16(a, b, c) MFMA16x16_host_stub(a, b, c)
#endif

__device__ __forceinline__ u16 f2bf(float f) {
    union { float f; unsigned u; } a; a.f = f;
    unsigned r = a.u + 0x7FFFu + ((a.u >> 16) & 1u);  // RNE
    return (u16)(r >> 16);
}

// ---------------- K0: fused f32 -> bf16 convert (x then qkv_w) ----------------
__global__ __launch_bounds__(256) void cvt_fused_kernel(const float* __restrict__ xin,
                                                        const float* __restrict__ win,
                                                        u16* __restrict__ xout,
                                                        u16* __restrict__ wout) {
    int i = (blockIdx.x * 256 + threadIdx.x) * 4;
    const float* src;
    u16* dst;
    int j;
    if (i < 4841472) {
        src = xin; dst = xout; j = i;
    } else {
        src = win; dst = wout; j = i - 4841472;
    }
    f32x4 v = *(const f32x4*)(src + j);
    u16x4 o;
#pragma unroll
    for (int k = 0; k < 4; ++k) o[k] = f2bf(v[k]);
    *(u16x4*)(dst + j) = o;
}

// ---------------- K1: QKV GEMM 6400x2304x768, 256x256 tile, BK=64, 8 waves ----------------
// R12-exact 2-phase structure (measured best ~47us; both schedule-surgery variants
// R11/R15 regressed). Swizzle (row&7)<<4 both sides, 0 bank conflicts measured.
__global__ __launch_bounds__(512, 2) void qkv_gemm_kernel(
    const u16* __restrict__ A,       // [6400][768] bf16 x
    const u16* __restrict__ Bm,      // [2304][768] bf16 qkv_w
    const float* __restrict__ bias,  // [2304]
    u16* __restrict__ qb, u16* __restrict__ kb, u16* __restrict__ vb) {
    __shared__ __align__(16) u16 As[2][256 * 64];  // 64 KB
    __shared__ __align__(16) u16 Bs[2][256 * 64];  // 64 KB
    const int tid = threadIdx.x;
    const int w = tid >> 6, l = tid & 63;
    const int wy = w >> 2, wx = w & 3;   // 2 M-waves x 4 N-waves (128x64 each)
    const int dl = l & 15, g4 = l >> 4;
    const int fr = (dl & 7) << 4;

    // bijective XCD chunking: nwg=225, q=28, r=1; bn-fast -> A panel L2 reuse
    const int wg = blockIdx.x;
    const int xcd = wg & 7, pos = wg >> 3;
    const int id2 = (xcd < 1 ? xcd * 29 : 29 + (xcd - 1) * 28) + pos;
    const int bm = id2 / 9, bn = id2 % 9;

    f32x4 acc[8][4] = {};

#define QKV_STAGE(bi, kt)                                                                   \
    {                                                                                       \
        _Pragma("unroll")                                                                   \
        for (int cc = 0; cc < 4; ++cc) {                                                    \
            int c = w * 256 + cc * 64 + l;                                                  \
            int row = c >> 3;                                                               \
            int cs = ((c & 7) << 4) ^ ((row & 7) << 4);                                     \
            __builtin_amdgcn_global_load_lds(                                               \
                GPTR((const char*)(A + (size_t)(bm * 256 + row) * 768 + (kt)) + cs),        \
                LPTR((char*)As[bi] + c * 16), 16, 0, 0);                                    \
            __builtin_amdgcn_global_load_lds(                                               \
                GPTR((const char*)(Bm + (size_t)(bn * 256 + row) * 768 + (kt)) + cs),       \
                LPTR((char*)Bs[bi] + c * 16), 16, 0, 0);                                    \
        }                                                                                   \
    }

    QKV_STAGE(0, 0)
    __syncthreads();
    int cur = 0;
#pragma unroll 1
    for (int t = 0; t < 12; ++t) {
        if (t < 11) QKV_STAGE(cur ^ 1, (t + 1) * 64)  // prefetch overlaps compute
#pragma unroll
        for (int s = 0; s < 2; ++s) {
            const int ce = ((s << 6) | (g4 << 4)) ^ fr;
            short8 af[8], bf[4];
#pragma unroll
            for (int mi = 0; mi < 8; ++mi)
                af[mi] = *(const short8*)((const char*)As[cur] + (wy * 128 + mi * 16 + dl) * 128 + ce);
#pragma unroll
            for (int ni = 0; ni < 4; ++ni)
                bf[ni] = *(const short8*)((const char*)Bs[cur] + (wx * 64 + ni * 16 + dl) * 128 + ce);
#pragma unroll
            for (int mi = 0; mi < 8; ++mi)
#pragma unroll
                for (int ni = 0; ni < 4; ++ni)
                    acc[mi][ni] = __builtin_amdgcn_mfma_f32_16x16x32_bf16(af[mi], bf[ni], acc[mi][ni], 0, 0, 0);
        }
        __syncthreads();
        cur ^= 1;
    }
#undef QKV_STAGE

    // epilogue: split into q/k/v (B,H,N,D) bf16; SCALE folded into q
#pragma unroll
    for (int ni = 0; ni < 4; ++ni) {
        int col = bn * 256 + wx * 64 + ni * 16 + dl;
        int s = (col >= 1536) ? 2 : (col >= 768) ? 1 : 0;
        int j = col - s * 768;
        int h = j >> 6, d = j & 63;
        float bv = bias[col];
        u16* dst = (s == 0) ? qb : (s == 1) ? kb : vb;
        float sc = (s == 0) ? 0.125f : 1.0f;
#pragma unroll
        for (int mi = 0; mi < 8; ++mi) {
#pragma unroll
            for (int r = 0; r < 4; ++r) {
                int row = bm * 256 + wy * 128 + mi * 16 + g4 * 4 + r;
                if (row < 6304) {
                    int bi = row / 197;
                    int n = row - bi * 197;
                    dst[((size_t)(bi * 12 + h) * 197 + n) * 64 + d] = f2bf((acc[mi][ni][r] + bv) * sc);
                }
            }
        }
    }
}

// ---------------- K2: attention per (b,h) x q-half, 4 waves (R12-proven) ----------------
#define VPAD 212
__global__ __launch_bounds__(256) void attn_kernel(
    const u16* __restrict__ qg_all, const u16* __restrict__ kg_all, const u16* __restrict__ vg_all,
    const int* __restrict__ y, const float* __restrict__ mask_attn,
    u16* __restrict__ omid) {
    __shared__ __align__(16) u16 Ks[208 * 64];    // XOR-swizzled rows
    __shared__ __align__(16) u16 Vst[64 * VPAD];  // V^T, padded rows
    const int bh = blockIdx.x >> 1, half = blockIdx.x & 1;
    const int b = bh / 12, h = bh % 12;
    const int tid = threadIdx.x, w = tid >> 6, l = tid & 63;
    const int dl = l & 15, g = l >> 4;
    const size_t base = (size_t)bh * 197 * 64;
    const u16* qg = qg_all + base;
    const u16* kg = kg_all + base;
    const u16* vg = vg_all + base;
    const short8 zero8 = {0, 0, 0, 0, 0, 0, 0, 0};
    const int ycls = y[b];

    for (int c = tid; c < 208 * 8; c += 256) {  // K tile, swizzled, zero pad rows 197..207
        int row = c >> 3, colb = (c & 7) * 16;
        short8 val = zero8;
        if (row < 197) val = *(const short8*)(kg + row * 64 + (c & 7) * 8);
        int bo = (row * 128 + colb) ^ ((row & 7) << 4);
        *(short8*)((char*)Ks + bo) = val;
    }
    for (int c = tid; c < 208 * 8; c += 256) {  // V transposed, zero pad keys 197..207
        int row = c >> 3, col = (c & 7) * 8;
        short8 val = zero8;
        if (row < 197) val = *(const short8*)(vg + row * 64 + col);
#pragma unroll
        for (int j = 0; j < 8; ++j) Vst[(col + j) * VPAD + row] = (u16)val[j];
    }
    __syncthreads();

    const int ci_end = half ? 13 : 7;
    for (int ci = half * 7 + w; ci < ci_end; ci += 4) {
        int qrow = ci * 16 + dl;
        const u16* qr = qg + (size_t)qrow * 64 + g * 8;
        short8 q0 = *(const short8*)(qr);
        short8 q1 = *(const short8*)(qr + 32);

        f32x4 sc[13];
#pragma unroll
        for (int jb = 0; jb < 13; ++jb) {
            int krow = jb * 16 + dl;
            int sw = (krow & 7) << 4;
            short8 k0 = *(const short8*)((const char*)Ks + ((krow * 128 + g * 16) ^ sw));
            short8 k1 = *(const short8*)((const char*)Ks + ((krow * 128 + 64 + g * 16) ^ sw));
            f32x4 t = {0.f, 0.f, 0.f, 0.f};
            t = __builtin_amdgcn_mfma_f32_16x16x32_bf16(k0, q0, t, 0, 0, 0);
            t = __builtin_amdgcn_mfma_f32_16x16x32_bf16(k1, q1, t, 0, 0, 0);
            sc[jb] = t;
        }
#pragma unroll
        for (int r = 0; r < 4; ++r)
            if (192 + g * 4 + r >= 197) sc[12][r] = -1e30f;

        float mx = -1e30f;
#pragma unroll
        for (int jb = 0; jb < 13; ++jb)
#pragma unroll
            for (int r = 0; r < 4; ++r) mx = fmaxf(mx, sc[jb][r]);
        mx = fmaxf(mx, __shfl_xor(mx, 16));
        mx = fmaxf(mx, __shfl_xor(mx, 32));
        float ssum = 0.f;
#pragma unroll
        for (int jb = 0; jb < 13; ++jb)
#pragma unroll
            for (int r = 0; r < 4; ++r) {
                float e = __expf(sc[jb][r] - mx);
                sc[jb][r] = e;
                ssum += e;
            }
        ssum += __shfl_xor(ssum, 16);
        ssum += __shfl_xor(ssum, 32);
        float inv = 1.0f / ssum;

        s16x4 pb[13];
#pragma unroll
        for (int jb = 0; jb < 13; ++jb) {
            s16x4 pv;
#pragma unroll
            for (int r = 0; r < 4; ++r) pv[r] = (short)f2bf(sc[jb][r] * inv);
            pb[jb] = pv;
        }

        // Uniform whole-wave MFMA; only the store is per-lane predicated (R5 lesson).
#pragma unroll
        for (int db = 0; db < 4; ++db) {
            f32x4 o = {0.f, 0.f, 0.f, 0.f};
#pragma unroll
            for (int jb = 0; jb < 13; ++jb) {
                s16x4 va = *(const s16x4*)&Vst[(db * 16 + dl) * VPAD + jb * 16 + g * 4];
                o = MFMA16x16(va, pb[jb], o);
            }
            if (qrow < 197) {
                int d = db * 16 + g * 4;
                f32x4 mv = *(const f32x4*)(mask_attn + ((size_t)ycls * 12 + h) * 64 + d);
                u16x4 ov;
#pragma unroll
                for (int r = 0; r < 4; ++r) ov[r] = f2bf(o[r] * mv[r]);
                *(u16x4*)(omid + ((size_t)(b * 256 + qrow)) * 768 + h * 64 + d) = ov;
            }
        }
    }
}

// ---------------- K4: proj GEMM, 128(M) x 128(N), BK=64, 4 waves, 2 blocks/CU ----------------
// grid 384 = (b, bn, mb) with mb adjacent (mask panel 2nd read L2-hot). 64 KB LDS
// -> 2 co-resident blocks/CU cross-hide the 2-phase barrier drain (fixes N128-merged's
// 0.75 blocks/CU). Same verified 2-phase template + (row&7)<<4 swizzle both sides.
__global__ __launch_bounds__(256, 2) void proj_gemm_kernel(
    const u16* __restrict__ A,          // omid [32][256][768] bf16
    const float* __restrict__ proj_w,   // [768][768] f32
    const float* __restrict__ mask_proj,// [100][768][768] f32
    const int* __restrict__ y,
    const float* __restrict__ bias,     // [768]
    float* __restrict__ out) {          // [32][197][768] f32
    __shared__ __align__(16) u16 Ap[2][128 * 64];  // 32 KB
    __shared__ __align__(16) u16 Bp[2][128 * 64];  // 32 KB
    const int tid = threadIdx.x;
    const int w = tid >> 6, l = tid & 63;
    const int wy = w >> 1, wx = w & 1;   // 2 M-waves x 2 N-waves (64x64 each)
    const int dl = l & 15, g4 = l >> 4;
    const int fr = (dl & 7) << 4;

    // bijective XCD chunking: nwg=384, q=48, r=0; order (b, bn, mb): mb adjacent,
    // bn within b -> A panel + mask panel L2 reuse on one XCD.
    const int wg = blockIdx.x;
    const int id2 = (wg & 7) * 48 + (wg >> 3);
    const int b = id2 / 12, rem = id2 % 12;
    const int bn = rem >> 1, mb = rem & 1;
    const size_t mbase = (size_t)y[b] * 589824;

    const int brow = tid >> 1;           // B-stage: N-row 0..127
    const int bcolf = (tid & 1) * 32;    // 32 f32 K-cols per thread
    const int bcb = bcolf * 2;           // byte col in bf16 LDS row
    const int bsw = (brow & 7) << 4;

    f32x4 pw[8], pm[8];

#define PROJ_LOADB(kt)                                                              \
    {                                                                               \
        size_t off = (size_t)(bn * 128 + brow) * 768 + (kt) + bcolf;                \
        _Pragma("unroll")                                                           \
        for (int j = 0; j < 8; ++j) {                                               \
            pw[j] = *(const f32x4*)(proj_w + off + j * 4);                          \
            pm[j] = *(const f32x4*)(mask_proj + mbase + off + j * 4);               \
        }                                                                           \
    }

#define PROJ_WRITEB(bi)                                                             \
    {                                                                               \
        char* bp = (char*)Bp[bi] + brow * 128;                                      \
        _Pragma("unroll")                                                           \
        for (int k = 0; k < 4; ++k) {                                               \
            short8 ov;                                                              \
            _Pragma("unroll")                                                       \
            for (int j = 0; j < 4; ++j) {                                           \
                ov[j] = (short)f2bf(pw[2 * k][j] * pm[2 * k][j]);                   \
                ov[4 + j] = (short)f2bf(pw[2 * k + 1][j] * pm[2 * k + 1][j]);       \
            }                                                                       \
            *(short8*)(bp + ((bcb + 16 * k) ^ bsw)) = ov;                           \
        }                                                                           \
    }

#define PROJ_STAGEA(bi, kt)                                                         \
    {                                                                               \
        _Pragma("unroll")                                                           \
        for (int cc = 0; cc < 4; ++cc) {                                            \
            int c = cc * 256 + tid;                                                 \
            int row = c >> 3;                                                       \
            int cs = ((c & 7) << 4) ^ ((row & 7) << 4);                             \
            __builtin_amdgcn_global_load_lds(                                       \
                GPTR((const char*)(A + (size_t)(b * 256 + mb * 128 + row) * 768 + (kt)) + cs), \
                LPTR((char*)Ap[bi] + c * 16), 16, 0, 0);                            \
        }                                                                           \
    }

    f32x4 acc[4][4] = {};
    PROJ_LOADB(0)
    PROJ_STAGEA(0, 0)
    PROJ_WRITEB(0)
    __syncthreads();
    int cur = 0;
#pragma unroll 1
    for (int t = 0; t < 12; ++t) {
        if (t < 11) {
            PROJ_STAGEA(cur ^ 1, (t + 1) * 64)  // async A prefetch
            PROJ_LOADB((t + 1) * 64)            // B f32 loads issue early...
        }
#pragma unroll
        for (int s = 0; s < 2; ++s) {
            const int ce = ((s << 6) | (g4 << 4)) ^ fr;
            short8 af[4], bf[4];
#pragma unroll
            for (int mi = 0; mi < 4; ++mi)
                af[mi] = *(const short8*)((const char*)Ap[cur] + (wy * 64 + mi * 16 + dl) * 128 + ce);
#pragma unroll
            for (int ni = 0; ni < 4; ++ni)
                bf[ni] = *(const short8*)((const char*)Bp[cur] + (wx * 64 + ni * 16 + dl) * 128 + ce);
#pragma unroll
            for (int mi = 0; mi < 4; ++mi)
#pragma unroll
                for (int ni = 0; ni < 4; ++ni)
                    acc[mi][ni] = __builtin_amdgcn_mfma_f32_16x16x32_bf16(af[mi], bf[ni], acc[mi][ni], 0, 0, 0);
        }
        if (t < 11) PROJ_WRITEB(cur ^ 1)        // ...convert+write late (latency hidden)
        __syncthreads();
        cur ^= 1;
    }

#pragma unroll
    for (int ni = 0; ni < 4; ++ni) {
        int col = bn * 128 + wx * 64 + ni * 16 + dl;
        float bv = bias[col];
#pragma unroll
        for (int mi = 0; mi < 4; ++mi) {
#pragma unroll
            for (int r = 0; r < 4; ++r) {
                int row = mb * 128 + wy * 64 + mi * 16 + g4 * 4 + r;
                if (row < 197)
                    out[((size_t)b * 197 + row) * 768 + col] = acc[mi][ni][r] + bv;
            }
        }
    }
#undef PROJ_LOADB
#undef PROJ_WRITEB
#undef PROJ_STAGEA
}

extern "C" void kernel_launch(void* const* d_in, const int* in_sizes, int n_in,
                              void* d_out, int out_size, void* d_ws, size_t ws_size,
                              hipStream_t stream) {
    const float* x = (const float*)d_in[0];
    const int* y = (const int*)d_in[1];
    const float* qkv_w = (const float*)d_in[2];
    const float* qkv_b = (const float*)d_in[3];
    const float* proj_w = (const float*)d_in[4];
    const float* proj_b = (const float*)d_in[5];
    const float* mask_attn = (const float*)d_in[6];
    const float* mask_proj = (const float*)d_in[7];
    float* out = (float*)d_out;

    // workspace layout (bf16 = u16), ~55.3 MB
    u16* xb = (u16*)d_ws;                       // [6400][768]
    u16* wqkvb = xb + (size_t)6400 * 768;       // [2304][768]
    u16* qb = wqkvb + (size_t)2304 * 768;       // [76288][64]
    u16* kb = qb + (size_t)76288 * 64;
    u16* vb = kb + (size_t)76288 * 64;
    u16* omid = vb + (size_t)76288 * 64;        // [32][256][768]

    cvt_fused_kernel<<<6456, 256, 0, stream>>>(x, qkv_w, xb, wqkvb);
    qkv_gemm_kernel<<<225, 512, 0, stream>>>(xb, wqkvb, qkv_b, qb, kb, vb);
    attn_kernel<<<768, 256, 0, stream>>>(qb, kb, vb, y, mask_attn, omid);
    proj_gemm_kernel<<<384, 256, 0, stream>>>(omid, proj_w, mask_proj, y, proj_b, out);
}

// Round 17
// 129.970 us; speedup vs baseline: 1.5595x; 1.5595x over previous
//
#include <hip/hip_runtime.h>

typedef unsigned short u16;
typedef __attribute__((ext_vector_type(8))) short short8;
typedef __attribute__((ext_vector_type(4))) short s16x4;
typedef __attribute__((ext_vector_type(4))) float f32x4;
typedef __attribute__((ext_vector_type(4))) u16 u16x4;

#define GPTR(p) ((const __attribute__((address_space(1))) void*)(p))
#define LPTR(p) ((__attribute__((address_space(3))) void*)(p))

#if __has_builtin(__builtin_amdgcn_mfma_f32_16x16x16bf16_1k)
#define MFMA16x16(a, b, c) __builtin_amdgcn_mfma_f32_16x16x16bf16_1k(a, b, c, 0, 0, 0)
#elif __has_builtin(__builtin_amdgcn_mfma_f32_16x16x16_bf16)
#define MFMA16x16(a, b, c) __builtin_amdgcn_mfma_f32_16x16x16_bf16(a, b, c, 0, 0, 0)
#else
__host__ __device__ static inline f32x4 MFMA16x16_host_stub(s16x4, s16x4, f32x4 c) { return c; }
#define MFMA16x16(a, b, c) MFMA16x16_host_stub(a, b, c)
#endif

__device__ __forceinline__ u16 f2bf(float f) {
    union { float f; unsigned u; } a; a.f = f;
    unsigned r = a.u + 0x7FFFu + ((a.u >> 16) & 1u);  // RNE
    return (u16)(r >> 16);
}

// ---------------- K0: fused f32 -> bf16 convert (x then qkv_w) ----------------
__global__ __launch_bounds__(256) void cvt_fused_kernel(const float* __restrict__ xin,
                                                        const float* __restrict__ win,
                                                        u16* __restrict__ xout,
                                                        u16* __restrict__ wout) {
    int i = (blockIdx.x * 256 + threadIdx.x) * 4;
    const float* src;
    u16* dst;
    int j;
    if (i < 4841472) {
        src = xin; dst = xout; j = i;
    } else {
        src = win; dst = wout; j = i - 4841472;
    }
    f32x4 v = *(const f32x4*)(src + j);
    u16x4 o;
#pragma unroll
    for (int k = 0; k < 4; ++k) o[k] = f2bf(v[k]);
    *(u16x4*)(dst + j) = o;
}

// ---------------- K1: QKV GEMM 6400x2304x768, 256x256 tile, BK=64, 8 waves ----------------
// R12-exact 2-phase structure (measured best; R11/R15 schedule surgery both regressed).
__global__ __launch_bounds__(512, 2) void qkv_gemm_kernel(
    const u16* __restrict__ A,       // [6400][768] bf16 x
    const u16* __restrict__ Bm,      // [2304][768] bf16 qkv_w
    const float* __restrict__ bias,  // [2304]
    u16* __restrict__ qb, u16* __restrict__ kb, u16* __restrict__ vb) {
    __shared__ __align__(16) u16 As[2][256 * 64];  // 64 KB
    __shared__ __align__(16) u16 Bs[2][256 * 64];  // 64 KB
    const int tid = threadIdx.x;
    const int w = tid >> 6, l = tid & 63;
    const int wy = w >> 2, wx = w & 3;   // 2 M-waves x 4 N-waves (128x64 each)
    const int dl = l & 15, g4 = l >> 4;
    const int fr = (dl & 7) << 4;

    // bijective XCD chunking: nwg=225, q=28, r=1; bn-fast -> A panel L2 reuse
    const int wg = blockIdx.x;
    const int xcd = wg & 7, pos = wg >> 3;
    const int id2 = (xcd < 1 ? xcd * 29 : 29 + (xcd - 1) * 28) + pos;
    const int bm = id2 / 9, bn = id2 % 9;

    f32x4 acc[8][4] = {};

#define QKV_STAGE(bi, kt)                                                                   \
    {                                                                                       \
        _Pragma("unroll")                                                                   \
        for (int cc = 0; cc < 4; ++cc) {                                                    \
            int c = w * 256 + cc * 64 + l;                                                  \
            int row = c >> 3;                                                               \
            int cs = ((c & 7) << 4) ^ ((row & 7) << 4);                                     \
            __builtin_amdgcn_global_load_lds(                                               \
                GPTR((const char*)(A + (size_t)(bm * 256 + row) * 768 + (kt)) + cs),        \
                LPTR((char*)As[bi] + c * 16), 16, 0, 0);                                    \
            __builtin_amdgcn_global_load_lds(                                               \
                GPTR((const char*)(Bm + (size_t)(bn * 256 + row) * 768 + (kt)) + cs),       \
                LPTR((char*)Bs[bi] + c * 16), 16, 0, 0);                                    \
        }                                                                                   \
    }

    QKV_STAGE(0, 0)
    __syncthreads();
    int cur = 0;
#pragma unroll 1
    for (int t = 0; t < 12; ++t) {
        if (t < 11) QKV_STAGE(cur ^ 1, (t + 1) * 64)  // prefetch overlaps compute
#pragma unroll
        for (int s = 0; s < 2; ++s) {
            const int ce = ((s << 6) | (g4 << 4)) ^ fr;
            short8 af[8], bf[4];
#pragma unroll
            for (int mi = 0; mi < 8; ++mi)
                af[mi] = *(const short8*)((const char*)As[cur] + (wy * 128 + mi * 16 + dl) * 128 + ce);
#pragma unroll
            for (int ni = 0; ni < 4; ++ni)
                bf[ni] = *(const short8*)((const char*)Bs[cur] + (wx * 64 + ni * 16 + dl) * 128 + ce);
#pragma unroll
            for (int mi = 0; mi < 8; ++mi)
#pragma unroll
                for (int ni = 0; ni < 4; ++ni)
                    acc[mi][ni] = __builtin_amdgcn_mfma_f32_16x16x32_bf16(af[mi], bf[ni], acc[mi][ni], 0, 0, 0);
        }
        __syncthreads();
        cur ^= 1;
    }
#undef QKV_STAGE

    // epilogue: split into q/k/v (B,H,N,D) bf16; SCALE folded into q
#pragma unroll
    for (int ni = 0; ni < 4; ++ni) {
        int col = bn * 256 + wx * 64 + ni * 16 + dl;
        int s = (col >= 1536) ? 2 : (col >= 768) ? 1 : 0;
        int j = col - s * 768;
        int h = j >> 6, d = j & 63;
        float bv = bias[col];
        u16* dst = (s == 0) ? qb : (s == 1) ? kb : vb;
        float sc = (s == 0) ? 0.125f : 1.0f;
#pragma unroll
        for (int mi = 0; mi < 8; ++mi) {
#pragma unroll
            for (int r = 0; r < 4; ++r) {
                int row = bm * 256 + wy * 128 + mi * 16 + g4 * 4 + r;
                if (row < 6304) {
                    int bi = row / 197;
                    int n = row - bi * 197;
                    dst[((size_t)(bi * 12 + h) * 197 + n) * 64 + d] = f2bf((acc[mi][ni][r] + bv) * sc);
                }
            }
        }
    }
}

// ---------------- K2: attention per (b,h) x q-half, 4 waves (R12-proven) ----------------
#define VPAD 212
__global__ __launch_bounds__(256) void attn_kernel(
    const u16* __restrict__ qg_all, const u16* __restrict__ kg_all, const u16* __restrict__ vg_all,
    const int* __restrict__ y, const float* __restrict__ mask_attn,
    u16* __restrict__ omid) {
    __shared__ __align__(16) u16 Ks[208 * 64];    // XOR-swizzled rows
    __shared__ __align__(16) u16 Vst[64 * VPAD];  // V^T, padded rows
    const int bh = blockIdx.x >> 1, half = blockIdx.x & 1;
    const int b = bh / 12, h = bh % 12;
    const int tid = threadIdx.x, w = tid >> 6, l = tid & 63;
    const int dl = l & 15, g = l >> 4;
    const size_t base = (size_t)bh * 197 * 64;
    const u16* qg = qg_all + base;
    const u16* kg = kg_all + base;
    const u16* vg = vg_all + base;
    const short8 zero8 = {0, 0, 0, 0, 0, 0, 0, 0};
    const int ycls = y[b];

    for (int c = tid; c < 208 * 8; c += 256) {  // K tile, swizzled, zero pad rows 197..207
        int row = c >> 3, colb = (c & 7) * 16;
        short8 val = zero8;
        if (row < 197) val = *(const short8*)(kg + row * 64 + (c & 7) * 8);
        int bo = (row * 128 + colb) ^ ((row & 7) << 4);
        *(short8*)((char*)Ks + bo) = val;
    }
    for (int c = tid; c < 208 * 8; c += 256) {  // V transposed, zero pad keys 197..207
        int row = c >> 3, col = (c & 7) * 8;
        short8 val = zero8;
        if (row < 197) val = *(const short8*)(vg + row * 64 + col);
#pragma unroll
        for (int j = 0; j < 8; ++j) Vst[(col + j) * VPAD + row] = (u16)val[j];
    }
    __syncthreads();

    const int ci_end = half ? 13 : 7;
    for (int ci = half * 7 + w; ci < ci_end; ci += 4) {
        int qrow = ci * 16 + dl;
        const u16* qr = qg + (size_t)qrow * 64 + g * 8;
        short8 q0 = *(const short8*)(qr);
        short8 q1 = *(const short8*)(qr + 32);

        f32x4 sc[13];
#pragma unroll
        for (int jb = 0; jb < 13; ++jb) {
            int krow = jb * 16 + dl;
            int sw = (krow & 7) << 4;
            short8 k0 = *(const short8*)((const char*)Ks + ((krow * 128 + g * 16) ^ sw));
            short8 k1 = *(const short8*)((const char*)Ks + ((krow * 128 + 64 + g * 16) ^ sw));
            f32x4 t = {0.f, 0.f, 0.f, 0.f};
            t = __builtin_amdgcn_mfma_f32_16x16x32_bf16(k0, q0, t, 0, 0, 0);
            t = __builtin_amdgcn_mfma_f32_16x16x32_bf16(k1, q1, t, 0, 0, 0);
            sc[jb] = t;
        }
#pragma unroll
        for (int r = 0; r < 4; ++r)
            if (192 + g * 4 + r >= 197) sc[12][r] = -1e30f;

        float mx = -1e30f;
#pragma unroll
        for (int jb = 0; jb < 13; ++jb)
#pragma unroll
            for (int r = 0; r < 4; ++r) mx = fmaxf(mx, sc[jb][r]);
        mx = fmaxf(mx, __shfl_xor(mx, 16));
        mx = fmaxf(mx, __shfl_xor(mx, 32));
        float ssum = 0.f;
#pragma unroll
        for (int jb = 0; jb < 13; ++jb)
#pragma unroll
            for (int r = 0; r < 4; ++r) {
                float e = __expf(sc[jb][r] - mx);
                sc[jb][r] = e;
                ssum += e;
            }
        ssum += __shfl_xor(ssum, 16);
        ssum += __shfl_xor(ssum, 32);
        float inv = 1.0f / ssum;

        s16x4 pb[13];
#pragma unroll
        for (int jb = 0; jb < 13; ++jb) {
            s16x4 pv;
#pragma unroll
            for (int r = 0; r < 4; ++r) pv[r] = (short)f2bf(sc[jb][r] * inv);
            pb[jb] = pv;
        }

        // Uniform whole-wave MFMA; only the store is per-lane predicated (R5 lesson).
#pragma unroll
        for (int db = 0; db < 4; ++db) {
            f32x4 o = {0.f, 0.f, 0.f, 0.f};
#pragma unroll
            for (int jb = 0; jb < 13; ++jb) {
                s16x4 va = *(const s16x4*)&Vst[(db * 16 + dl) * VPAD + jb * 16 + g * 4];
                o = MFMA16x16(va, pb[jb], o);
            }
            if (qrow < 197) {
                int d = db * 16 + g * 4;
                f32x4 mv = *(const f32x4*)(mask_attn + ((size_t)ycls * 12 + h) * 64 + d);
                u16x4 ov;
#pragma unroll
                for (int r = 0; r < 4; ++r) ov[r] = f2bf(o[r] * mv[r]);
                *(u16x4*)(omid + ((size_t)(b * 256 + qrow)) * 768 + h * 64 + d) = ov;
            }
        }
    }
}

// ---------------- K4: proj GEMM, 256(M=197pad) x 128(N), BK=64 (R10-measured best) ----------------
// One block per (b, bn): mask panel staged once, coalesced B loads (4 lanes/row x
// 64 consecutive f32). R16's M-split regressed 4.5x (uncoalesced 2-lanes/row B loads).
__global__ __launch_bounds__(512, 2) void proj_gemm_kernel(
    const u16* __restrict__ A,          // omid [32][256][768] bf16
    const float* __restrict__ proj_w,   // [768][768] f32
    const float* __restrict__ mask_proj,// [100][768][768] f32
    const int* __restrict__ y,
    const float* __restrict__ bias,     // [768]
    float* __restrict__ out) {          // [32][197][768] f32
    __shared__ __align__(16) u16 Ap[2][256 * 64];  // 64 KB
    __shared__ __align__(16) u16 Bp[2][128 * 64];  // 32 KB
    const int tid = threadIdx.x;
    const int w = tid >> 6, l = tid & 63;
    const int wy = w >> 1, wx = w & 1;   // 4 M-waves x 2 N-waves (64x64 each)
    const int dl = l & 15, g4 = l >> 4;
    const int fr = (dl & 7) << 4;

    // bijective XCD chunking: nwg=192, q=24, r=0
    const int wg = blockIdx.x;
    const int id2 = (wg & 7) * 24 + (wg >> 3);
    const int b = id2 / 6, bn = id2 % 6;
    const size_t mbase = (size_t)y[b] * 589824;

    const int brow = tid >> 2;             // B-stage: row 0..127
    const int becol = (tid & 3) * 16;      // 16 f32 cols per thread
    const int bcb = becol * 2;             // byte col in bf16 LDS row
    const int bsw = (brow & 7) << 4;

    f32x4 pw[4], pm[4];

#define PROJ_LOADB(kt)                                                              \
    {                                                                               \
        size_t off = (size_t)(bn * 128 + brow) * 768 + (kt) + becol;                \
        _Pragma("unroll")                                                           \
        for (int j = 0; j < 4; ++j) {                                               \
            pw[j] = *(const f32x4*)(proj_w + off + j * 4);                          \
            pm[j] = *(const f32x4*)(mask_proj + mbase + off + j * 4);               \
        }                                                                           \
    }

#define PROJ_WRITEB(bi)                                                             \
    {                                                                               \
        short8 o0, o1;                                                              \
        _Pragma("unroll")                                                           \
        for (int j = 0; j < 4; ++j) {                                               \
            o0[j] = (short)f2bf(pw[0][j] * pm[0][j]);                               \
            o0[4 + j] = (short)f2bf(pw[1][j] * pm[1][j]);                           \
            o1[j] = (short)f2bf(pw[2][j] * pm[2][j]);                               \
            o1[4 + j] = (short)f2bf(pw[3][j] * pm[3][j]);                           \
        }                                                                           \
        char* bp = (char*)Bp[bi] + brow * 128;                                      \
        *(short8*)(bp + (bcb ^ bsw)) = o0;                                          \
        *(short8*)(bp + ((bcb + 16) ^ bsw)) = o1;                                   \
    }

#define PROJ_STAGEA(bi, kt)                                                         \
    {                                                                               \
        _Pragma("unroll")                                                           \
        for (int cc = 0; cc < 4; ++cc) {                                            \
            int c = w * 256 + cc * 64 + l;                                          \
            int row = c >> 3;                                                       \
            int cs = ((c & 7) << 4) ^ ((row & 7) << 4);                             \
            __builtin_amdgcn_global_load_lds(                                       \
                GPTR((const char*)(A + (size_t)(b * 256 + row) * 768 + (kt)) + cs), \
                LPTR((char*)Ap[bi] + c * 16), 16, 0, 0);                            \
        }                                                                           \
    }

    f32x4 acc[4][4] = {};
    PROJ_LOADB(0)
    PROJ_STAGEA(0, 0)
    PROJ_WRITEB(0)
    __syncthreads();
    int cur = 0;
#pragma unroll 1
    for (int t = 0; t < 12; ++t) {
        if (t < 11) {
            PROJ_STAGEA(cur ^ 1, (t + 1) * 64)  // async A prefetch
            PROJ_LOADB((t + 1) * 64)            // B f32 loads issue early...
        }
#pragma unroll
        for (int s = 0; s < 2; ++s) {
            const int ce = ((s << 6) | (g4 << 4)) ^ fr;
            short8 af[4], bf[4];
#pragma unroll
            for (int mi = 0; mi < 4; ++mi)
                af[mi] = *(const short8*)((const char*)Ap[cur] + (wy * 64 + mi * 16 + dl) * 128 + ce);
#pragma unroll
            for (int ni = 0; ni < 4; ++ni)
                bf[ni] = *(const short8*)((const char*)Bp[cur] + (wx * 64 + ni * 16 + dl) * 128 + ce);
#pragma unroll
            for (int mi = 0; mi < 4; ++mi)
#pragma unroll
                for (int ni = 0; ni < 4; ++ni)
                    acc[mi][ni] = __builtin_amdgcn_mfma_f32_16x16x32_bf16(af[mi], bf[ni], acc[mi][ni], 0, 0, 0);
        }
        if (t < 11) PROJ_WRITEB(cur ^ 1)        // ...convert+write late (latency hidden)
        __syncthreads();
        cur ^= 1;
    }

#pragma unroll
    for (int ni = 0; ni < 4; ++ni) {
        int col = bn * 128 + wx * 64 + ni * 16 + dl;
        float bv = bias[col];
#pragma unroll
        for (int mi = 0; mi < 4; ++mi) {
#pragma unroll
            for (int r = 0; r < 4; ++r) {
                int row = wy * 64 + mi * 16 + g4 * 4 + r;
                if (row < 197)
                    out[((size_t)b * 197 + row) * 768 + col] = acc[mi][ni][r] + bv;
            }
        }
    }
#undef PROJ_LOADB
#undef PROJ_WRITEB
#undef PROJ_STAGEA
}

extern "C" void kernel_launch(void* const* d_in, const int* in_sizes, int n_in,
                              void* d_out, int out_size, void* d_ws, size_t ws_size,
                              hipStream_t stream) {
    const float* x = (const float*)d_in[0];
    const int* y = (const int*)d_in[1];
    const float* qkv_w = (const float*)d_in[2];
    const float* qkv_b = (const float*)d_in[3];
    const float* proj_w = (const float*)d_in[4];
    const float* proj_b = (const float*)d_in[5];
    const float* mask_attn = (const float*)d_in[6];
    const float* mask_proj = (const float*)d_in[7];
    float* out = (float*)d_out;

    // workspace layout (bf16 = u16), ~55.3 MB
    u16* xb = (u16*)d_ws;                       // [6400][768]
    u16* wqkvb = xb + (size_t)6400 * 768;       // [2304][768]
    u16* qb = wqkvb + (size_t)2304 * 768;       // [76288][64]
    u16* kb = qb + (size_t)76288 * 64;
    u16* vb = kb + (size_t)76288 * 64;
    u16* omid = vb + (size_t)76288 * 64;        // [32][256][768]

    cvt_fused_kernel<<<6456, 256, 0, stream>>>(x, qkv_w, xb, wqkvb);
    qkv_gemm_kernel<<<225, 512, 0, stream>>>(xb, wqkvb, qkv_b, qb, kb, vb);
    attn_kernel<<<768, 256, 0, stream>>>(qb, kb, vb, y, mask_attn, omid);
    proj_gemm_kernel<<<192, 512, 0, stream>>>(omid, proj_w, mask_proj, y, proj_b, out);
}

// Round 18
// 118.546 us; speedup vs baseline: 1.7098x; 1.0964x over previous
//
#include <hip/hip_runtime.h>

typedef unsigned short u16;
typedef __attribute__((ext_vector_type(8))) short short8;
typedef __attribute__((ext_vector_type(4))) short s16x4;
typedef __attribute__((ext_vector_type(4))) float f32x4;
typedef __attribute__((ext_vector_type(4))) u16 u16x4;

#define GPTR(p) ((const __attribute__((address_space(1))) void*)(p))
#define LPTR(p) ((__attribute__((address_space(3))) void*)(p))

#if __has_builtin(__builtin_amdgcn_mfma_f32_16x16x16bf16_1k)
#define MFMA16x16(a, b, c) __builtin_amdgcn_mfma_f32_16x16x16bf16_1k(a, b, c, 0, 0, 0)
#elif __has_builtin(__builtin_amdgcn_mfma_f32_16x16x16_bf16)
#define MFMA16x16(a, b, c) __builtin_amdgcn_mfma_f32_16x16x16_bf16(a, b, c, 0, 0, 0)
#else
__host__ __device__ static inline f32x4 MFMA16x16_host_stub(s16x4, s16x4, f32x4 c) { return c; }
#define MFMA16x16(a, b, c) MFMA16x16_host_stub(a, b, c)
#endif

__device__ __forceinline__ u16 f2bf(float f) {
    union { float f; unsigned u; } a; a.f = f;
    unsigned r = a.u + 0x7FFFu + ((a.u >> 16) & 1u);  // RNE
    return (u16)(r >> 16);
}

// ---------------- K0: fused f32 -> bf16 convert (x then qkv_w) ----------------
__global__ __launch_bounds__(256) void cvt_fused_kernel(const float* __restrict__ xin,
                                                        const float* __restrict__ win,
                                                        u16* __restrict__ xout,
                                                        u16* __restrict__ wout) {
    int i = (blockIdx.x * 256 + threadIdx.x) * 4;
    const float* src;
    u16* dst;
    int j;
    if (i < 4841472) {
        src = xin; dst = xout; j = i;
    } else {
        src = win; dst = wout; j = i - 4841472;
    }
    f32x4 v = *(const f32x4*)(src + j);
    u16x4 o;
#pragma unroll
    for (int k = 0; k < 4; ++k) o[k] = f2bf(v[k]);
    *(u16x4*)(dst + j) = o;
}

// ---------------- K1: QKV GEMM 6400x2304x768 — 8-phase schedule (R15 verbatim) ----------------
// Ledger: R15-R17 isolates 8ph as ~3us faster than 2ph at this shape.
__global__ __launch_bounds__(512, 2) void qkv_gemm_kernel(
    const u16* __restrict__ A,       // [6400][768] bf16 x
    const u16* __restrict__ Bm,      // [2304][768] bf16 qkv_w
    const float* __restrict__ bias,  // [2304]
    u16* __restrict__ qb, u16* __restrict__ kb, u16* __restrict__ vb) {
    __shared__ __align__(16) u16 As[2][256 * 64];  // 64 KB
    __shared__ __align__(16) u16 Bs[2][256 * 64];  // 64 KB
    const int tid = threadIdx.x;
    const int w = tid >> 6, l = tid & 63;
    const int wy = w >> 2, wx = w & 3;   // 2 M-waves x 4 N-waves
    const int dl = l & 15, g4 = l >> 4;
    const int fr = (dl & 7) << 4;

    // bijective XCD chunking: nwg=225, q=28, r=1
    const int wg = blockIdx.x;
    const int xcd = wg & 7, pos = wg >> 3;
    const int id2 = (xcd < 1 ? xcd * 29 : 29 + (xcd - 1) * 28) + pos;
    const int bm = id2 / 9, bn = id2 % 9;

#define STG(tau, k)                                                                          \
    if ((tau) < 12) {                                                                        \
        const u16* P = ((k) & 1) ? Bm : A;                                                   \
        const int tb = ((k) & 1) ? bn : bm;                                                  \
        char* Lb = (char*)(((k) & 1) ? Bs[(tau) & 1] : As[(tau) & 1]);                       \
        _Pragma("unroll")                                                                    \
        for (int j = 0; j < 2; ++j) {                                                        \
            int c = j * 512 + tid;                                                           \
            int row = (((k) >> 1) << 7) + (c >> 3);                                          \
            int cs = ((c & 7) << 4) ^ ((row & 7) << 4);                                      \
            __builtin_amdgcn_global_load_lds(                                                \
                GPTR((const char*)(P + (size_t)(tb * 256 + row) * 768 + (tau) * 64) + cs),   \
                LPTR(Lb + row * 128 + ((c & 7) << 4)), 16, 0, 0);                            \
        }                                                                                    \
    }

#define RD_A(qm, Tb)                                                                         \
    _Pragma("unroll")                                                                        \
    for (int mi = 0; mi < 4; ++mi)                                                           \
    _Pragma("unroll")                                                                        \
        for (int s = 0; s < 2; ++s)                                                          \
            af[mi][s] = *(const short8*)((const char*)As[(Tb)] +                             \
                ((qm) * 128 + wy * 64 + mi * 16 + dl) * 128 + (((s << 6) | (g4 << 4)) ^ fr));

#define RD_B(qn, Tb)                                                                         \
    _Pragma("unroll")                                                                        \
    for (int ni = 0; ni < 2; ++ni)                                                           \
    _Pragma("unroll")                                                                        \
        for (int s = 0; s < 2; ++s)                                                          \
            bf[ni][s] = *(const short8*)((const char*)Bs[(Tb)] +                             \
                ((qn) * 128 + wx * 32 + ni * 16 + dl) * 128 + (((s << 6) | (g4 << 4)) ^ fr));

#define MM(qm, qn)                                                                           \
    __builtin_amdgcn_s_setprio(1);                                                           \
    _Pragma("unroll")                                                                        \
    for (int s = 0; s < 2; ++s)                                                              \
    _Pragma("unroll")                                                                        \
        for (int mi = 0; mi < 4; ++mi)                                                       \
        _Pragma("unroll")                                                                    \
            for (int ni = 0; ni < 2; ++ni)                                                   \
                acc[qm][qn][mi][ni] = __builtin_amdgcn_mfma_f32_16x16x32_bf16(               \
                    af[mi][s], bf[ni][s], acc[qm][qn][mi][ni], 0, 0, 0);                     \
    __builtin_amdgcn_s_setprio(0);

#define FENCE asm volatile("" ::: "memory")
#define VM(n) asm volatile("s_waitcnt vmcnt(" #n ")" ::: "memory")
#define BAR __builtin_amdgcn_s_barrier()

    f32x4 acc[2][2][4][2] = {};
    short8 af[4][2], bf[2][2];

    // prologue: A0(0) B0(0) A1(0) B1(0) A0(1) B0(1) -> 12 loads in flight
    STG(0, 0) STG(0, 1) STG(0, 2) STG(0, 3) STG(1, 0) STG(1, 1)

#pragma unroll 1
    for (int T = 0; T < 12; ++T) {
        const int Tb = T & 1;
        if (T < 11) { VM(8); } else { VM(4); }
        BAR; FENCE;
        RD_A(0, Tb) RD_B(0, Tb)
        STG(T + 1, 2)
        MM(0, 0)
        FENCE; BAR; FENCE;
        RD_B(1, Tb)
        STG(T + 1, 3)
        MM(0, 1)
        FENCE;
        if (T < 11) { VM(8); } else { VM(0); }
        BAR; FENCE;
        RD_A(1, Tb) RD_B(0, Tb)
        STG(T + 2, 0)
        MM(1, 0)
        FENCE; BAR; FENCE;
        RD_B(1, Tb)
        STG(T + 2, 1)
        MM(1, 1)
        FENCE;
    }
#undef STG
#undef RD_A
#undef RD_B
#undef MM

    // epilogue: split into q/k/v (B,H,N,D) bf16; SCALE folded into q
#pragma unroll
    for (int qn = 0; qn < 2; ++qn)
#pragma unroll
        for (int ni = 0; ni < 2; ++ni) {
            int col = bn * 256 + qn * 128 + wx * 32 + ni * 16 + dl;
            int s = (col >= 1536) ? 2 : (col >= 768) ? 1 : 0;
            int j = col - s * 768;
            int h = j >> 6, d = j & 63;
            float bv = bias[col];
            u16* dst = (s == 0) ? qb : (s == 1) ? kb : vb;
            float sc = (s == 0) ? 0.125f : 1.0f;
#pragma unroll
            for (int qm = 0; qm < 2; ++qm)
#pragma unroll
                for (int mi = 0; mi < 4; ++mi)
#pragma unroll
                    for (int r = 0; r < 4; ++r) {
                        int row = bm * 256 + qm * 128 + wy * 64 + mi * 16 + g4 * 4 + r;
                        if (row < 6304) {
                            int bi = row / 197;
                            int n = row - bi * 197;
                            dst[((size_t)(bi * 12 + h) * 197 + n) * 64 + d] =
                                f2bf((acc[qm][qn][mi][ni][r] + bv) * sc);
                        }
                    }
        }
}

// ---------------- K2: attention per (b,h) x q-half, 4 waves (R12-proven) ----------------
#define VPAD 212
__global__ __launch_bounds__(256) void attn_kernel(
    const u16* __restrict__ qg_all, const u16* __restrict__ kg_all, const u16* __restrict__ vg_all,
    const int* __restrict__ y, const float* __restrict__ mask_attn,
    u16* __restrict__ omid) {
    __shared__ __align__(16) u16 Ks[208 * 64];    // XOR-swizzled rows
    __shared__ __align__(16) u16 Vst[64 * VPAD];  // V^T, padded rows
    const int bh = blockIdx.x >> 1, half = blockIdx.x & 1;
    const int b = bh / 12, h = bh % 12;
    const int tid = threadIdx.x, w = tid >> 6, l = tid & 63;
    const int dl = l & 15, g = l >> 4;
    const size_t base = (size_t)bh * 197 * 64;
    const u16* qg = qg_all + base;
    const u16* kg = kg_all + base;
    const u16* vg = vg_all + base;
    const short8 zero8 = {0, 0, 0, 0, 0, 0, 0, 0};
    const int ycls = y[b];

    for (int c = tid; c < 208 * 8; c += 256) {  // K tile, swizzled, zero pad rows 197..207
        int row = c >> 3, colb = (c & 7) * 16;
        short8 val = zero8;
        if (row < 197) val = *(const short8*)(kg + row * 64 + (c & 7) * 8);
        int bo = (row * 128 + colb) ^ ((row & 7) << 4);
        *(short8*)((char*)Ks + bo) = val;
    }
    for (int c = tid; c < 208 * 8; c += 256) {  // V transposed, zero pad keys 197..207
        int row = c >> 3, col = (c & 7) * 8;
        short8 val = zero8;
        if (row < 197) val = *(const short8*)(vg + row * 64 + col);
#pragma unroll
        for (int j = 0; j < 8; ++j) Vst[(col + j) * VPAD + row] = (u16)val[j];
    }
    __syncthreads();

    const int ci_end = half ? 13 : 7;
    for (int ci = half * 7 + w; ci < ci_end; ci += 4) {
        int qrow = ci * 16 + dl;
        const u16* qr = qg + (size_t)qrow * 64 + g * 8;
        short8 q0 = *(const short8*)(qr);
        short8 q1 = *(const short8*)(qr + 32);

        f32x4 sc[13];
#pragma unroll
        for (int jb = 0; jb < 13; ++jb) {
            int krow = jb * 16 + dl;
            int sw = (krow & 7) << 4;
            short8 k0 = *(const short8*)((const char*)Ks + ((krow * 128 + g * 16) ^ sw));
            short8 k1 = *(const short8*)((const char*)Ks + ((krow * 128 + 64 + g * 16) ^ sw));
            f32x4 t = {0.f, 0.f, 0.f, 0.f};
            t = __builtin_amdgcn_mfma_f32_16x16x32_bf16(k0, q0, t, 0, 0, 0);
            t = __builtin_amdgcn_mfma_f32_16x16x32_bf16(k1, q1, t, 0, 0, 0);
            sc[jb] = t;
        }
#pragma unroll
        for (int r = 0; r < 4; ++r)
            if (192 + g * 4 + r >= 197) sc[12][r] = -1e30f;

        float mx = -1e30f;
#pragma unroll
        for (int jb = 0; jb < 13; ++jb)
#pragma unroll
            for (int r = 0; r < 4; ++r) mx = fmaxf(mx, sc[jb][r]);
        mx = fmaxf(mx, __shfl_xor(mx, 16));
        mx = fmaxf(mx, __shfl_xor(mx, 32));
        float ssum = 0.f;
#pragma unroll
        for (int jb = 0; jb < 13; ++jb)
#pragma unroll
            for (int r = 0; r < 4; ++r) {
                float e = __expf(sc[jb][r] - mx);
                sc[jb][r] = e;
                ssum += e;
            }
        ssum += __shfl_xor(ssum, 16);
        ssum += __shfl_xor(ssum, 32);
        float inv = 1.0f / ssum;

        s16x4 pb[13];
#pragma unroll
        for (int jb = 0; jb < 13; ++jb) {
            s16x4 pv;
#pragma unroll
            for (int r = 0; r < 4; ++r) pv[r] = (short)f2bf(sc[jb][r] * inv);
            pb[jb] = pv;
        }

        // Uniform whole-wave MFMA; only the store is per-lane predicated (R5 lesson).
#pragma unroll
        for (int db = 0; db < 4; ++db) {
            f32x4 o = {0.f, 0.f, 0.f, 0.f};
#pragma unroll
            for (int jb = 0; jb < 13; ++jb) {
                s16x4 va = *(const s16x4*)&Vst[(db * 16 + dl) * VPAD + jb * 16 + g * 4];
                o = MFMA16x16(va, pb[jb], o);
            }
            if (qrow < 197) {
                int d = db * 16 + g * 4;
                f32x4 mv = *(const f32x4*)(mask_attn + ((size_t)ycls * 12 + h) * 64 + d);
                u16x4 ov;
#pragma unroll
                for (int r = 0; r < 4; ++r) ov[r] = f2bf(o[r] * mv[r]);
                *(u16x4*)(omid + ((size_t)(b * 256 + qrow)) * 768 + h * 64 + d) = ov;
            }
        }
    }
}

// ---------------- K4: proj GEMM, 256(M=197pad) x 64(N), BK=64 (R12 verbatim) ----------------
// Ledger: R17-R12 isolates N64x384blk as ~9us faster than N128x192blk (occupancy
// beats redundancy). Coalesced B loads: 8 lanes/row x 8 consecutive f32.
__global__ __launch_bounds__(512, 4) void proj_gemm_kernel(
    const u16* __restrict__ A,          // omid [32][256][768] bf16
    const float* __restrict__ proj_w,   // [768][768] f32
    const float* __restrict__ mask_proj,// [100][768][768] f32
    const int* __restrict__ y,
    const float* __restrict__ bias,     // [768]
    float* __restrict__ out) {          // [32][197][768] f32
    __shared__ __align__(16) u16 Ap[2][256 * 64];  // 64 KB
    __shared__ __align__(16) u16 Bp[2][64 * 64];   // 16 KB
    const int tid = threadIdx.x;
    const int w = tid >> 6, l = tid & 63;
    const int wy = w >> 1, wx = w & 1;   // 4 M-waves x 2 N-waves (64x32 each)
    const int dl = l & 15, g4 = l >> 4;
    const int fr = (dl & 7) << 4;

    // bijective XCD chunking: nwg=384, q=48, r=0; bn-fast -> omid panel L2 reuse
    const int wg = blockIdx.x;
    const int id2 = (wg & 7) * 48 + (wg >> 3);
    const int b = id2 / 12, bn = id2 % 12;
    const size_t mbase = (size_t)y[b] * 589824;

    const int brow = tid >> 3;           // B-stage: N-row 0..63
    const int bcolf = (tid & 7) * 8;     // 8 f32 K-cols per thread
    const int bcb = bcolf * 2;           // byte col in bf16 LDS row
    const int bsw = (brow & 7) << 4;

    f32x4 pw[2], pm[2];

#define PROJ_LOADB(kt)                                                              \
    {                                                                               \
        size_t off = (size_t)(bn * 64 + brow) * 768 + (kt) + bcolf;                 \
        pw[0] = *(const f32x4*)(proj_w + off);                                      \
        pw[1] = *(const f32x4*)(proj_w + off + 4);                                  \
        pm[0] = *(const f32x4*)(mask_proj + mbase + off);                           \
        pm[1] = *(const f32x4*)(mask_proj + mbase + off + 4);                       \
    }

#define PROJ_WRITEB(bi)                                                             \
    {                                                                               \
        short8 o0;                                                                  \
        _Pragma("unroll")                                                           \
        for (int j = 0; j < 4; ++j) {                                               \
            o0[j] = (short)f2bf(pw[0][j] * pm[0][j]);                               \
            o0[4 + j] = (short)f2bf(pw[1][j] * pm[1][j]);                           \
        }                                                                           \
        *(short8*)((char*)Bp[bi] + brow * 128 + (bcb ^ bsw)) = o0;                  \
    }

#define PROJ_STAGEA(bi, kt)                                                         \
    {                                                                               \
        _Pragma("unroll")                                                           \
        for (int cc = 0; cc < 4; ++cc) {                                            \
            int c = w * 256 + cc * 64 + l;                                          \
            int row = c >> 3;                                                       \
            int cs = ((c & 7) << 4) ^ ((row & 7) << 4);                             \
            __builtin_amdgcn_global_load_lds(                                       \
                GPTR((const char*)(A + (size_t)(b * 256 + row) * 768 + (kt)) + cs), \
                LPTR((char*)Ap[bi] + c * 16), 16, 0, 0);                            \
        }                                                                           \
    }

    f32x4 acc[4][2] = {};
    PROJ_LOADB(0)
    PROJ_STAGEA(0, 0)
    PROJ_WRITEB(0)
    __syncthreads();
    int cur = 0;
#pragma unroll 1
    for (int t = 0; t < 12; ++t) {
        if (t < 11) {
            PROJ_STAGEA(cur ^ 1, (t + 1) * 64)  // async A prefetch
            PROJ_LOADB((t + 1) * 64)            // B f32 loads issue early...
        }
#pragma unroll
        for (int s = 0; s < 2; ++s) {
            const int ce = ((s << 6) | (g4 << 4)) ^ fr;
            short8 af[4], bf[2];
#pragma unroll
            for (int mi = 0; mi < 4; ++mi)
                af[mi] = *(const short8*)((const char*)Ap[cur] + (wy * 64 + mi * 16 + dl) * 128 + ce);
#pragma unroll
            for (int ni = 0; ni < 2; ++ni)
                bf[ni] = *(const short8*)((const char*)Bp[cur] + (wx * 32 + ni * 16 + dl) * 128 + ce);
#pragma unroll
            for (int mi = 0; mi < 4; ++mi)
#pragma unroll
                for (int ni = 0; ni < 2; ++ni)
                    acc[mi][ni] = __builtin_amdgcn_mfma_f32_16x16x32_bf16(af[mi], bf[ni], acc[mi][ni], 0, 0, 0);
        }
        if (t < 11) PROJ_WRITEB(cur ^ 1)        // ...convert+write late (latency hidden)
        __syncthreads();
        cur ^= 1;
    }

#pragma unroll
    for (int ni = 0; ni < 2; ++ni) {
        int col = bn * 64 + wx * 32 + ni * 16 + dl;
        float bv = bias[col];
#pragma unroll
        for (int mi = 0; mi < 4; ++mi) {
#pragma unroll
            for (int r = 0; r < 4; ++r) {
                int row = wy * 64 + mi * 16 + g4 * 4 + r;
                if (row < 197)
                    out[((size_t)b * 197 + row) * 768 + col] = acc[mi][ni][r] + bv;
            }
        }
    }
#undef PROJ_LOADB
#undef PROJ_WRITEB
#undef PROJ_STAGEA
}

extern "C" void kernel_launch(void* const* d_in, const int* in_sizes, int n_in,
                              void* d_out, int out_size, void* d_ws, size_t ws_size,
                              hipStream_t stream) {
    const float* x = (const float*)d_in[0];
    const int* y = (const int*)d_in[1];
    const float* qkv_w = (const float*)d_in[2];
    const float* qkv_b = (const float*)d_in[3];
    const float* proj_w = (const float*)d_in[4];
    const float* proj_b = (const float*)d_in[5];
    const float* mask_attn = (const float*)d_in[6];
    const float* mask_proj = (const float*)d_in[7];
    float* out = (float*)d_out;

    // workspace layout (bf16 = u16), ~55.3 MB
    u16* xb = (u16*)d_ws;                       // [6400][768]
    u16* wqkvb = xb + (size_t)6400 * 768;       // [2304][768]
    u16* qb = wqkvb + (size_t)2304 * 768;       // [76288][64]
    u16* kb = qb + (size_t)76288 * 64;
    u16* vb = kb + (size_t)76288 * 64;
    u16* omid = vb + (size_t)76288 * 64;        // [32][256][768]

    cvt_fused_kernel<<<6456, 256, 0, stream>>>(x, qkv_w, xb, wqkvb);
    qkv_gemm_kernel<<<225, 512, 0, stream>>>(xb, wqkvb, qkv_b, qb, kb, vb);
    attn_kernel<<<768, 256, 0, stream>>>(qb, kb, vb, y, mask_attn, omid);
    proj_gemm_kernel<<<384, 512, 0, stream>>>(omid, proj_w, mask_proj, y, proj_b, out);
}

// Round 19
// 117.136 us; speedup vs baseline: 1.7304x; 1.0120x over previous
//
#include <hip/hip_runtime.h>

typedef unsigned short u16;
typedef __attribute__((ext_vector_type(8))) short short8;
typedef __attribute__((ext_vector_type(4))) short s16x4;
typedef __attribute__((ext_vector_type(4))) float f32x4;
typedef __attribute__((ext_vector_type(4))) u16 u16x4;

#define GPTR(p) ((const __attribute__((address_space(1))) void*)(p))
#define LPTR(p) ((__attribute__((address_space(3))) void*)(p))

#if __has_builtin(__builtin_amdgcn_mfma_f32_16x16x16bf16_1k)
#define MFMA16x16(a, b, c) __builtin_amdgcn_mfma_f32_16x16x16bf16_1k(a, b, c, 0, 0, 0)
#elif __has_builtin(__builtin_amdgcn_mfma_f32_16x16x16_bf16)
#define MFMA16x16(a, b, c) __builtin_amdgcn_mfma_f32_16x16x16_bf16(a, b, c, 0, 0, 0)
#else
__host__ __device__ static inline f32x4 MFMA16x16_host_stub(s16x4, s16x4, f32x4 c) { return c; }
#define MFMA16x16(a, b, c) MFMA16x16_host_stub(a, b, c)
#endif

__device__ __forceinline__ u16 f2bf(float f) {
    union { float f; unsigned u; } a; a.f = f;
    unsigned r = a.u + 0x7FFFu + ((a.u >> 16) & 1u);  // RNE
    return (u16)(r >> 16);
}

// ---------------- K0: fused f32 -> bf16 convert (x then qkv_w) ----------------
__global__ __launch_bounds__(256) void cvt_fused_kernel(const float* __restrict__ xin,
                                                        const float* __restrict__ win,
                                                        u16* __restrict__ xout,
                                                        u16* __restrict__ wout) {
    int i = (blockIdx.x * 256 + threadIdx.x) * 4;
    const float* src;
    u16* dst;
    int j;
    if (i < 4841472) {
        src = xin; dst = xout; j = i;
    } else {
        src = win; dst = wout; j = i - 4841472;
    }
    f32x4 v = *(const f32x4*)(src + j);
    u16x4 o;
#pragma unroll
    for (int k = 0; k < 4; ++k) o[k] = f2bf(v[k]);
    *(u16x4*)(dst + j) = o;
}

// ---------------- K1: QKV GEMM 6400x2304x768 — 8-phase schedule (R15/R18 verbatim) ----------------
__global__ __launch_bounds__(512, 2) void qkv_gemm_kernel(
    const u16* __restrict__ A,       // [6400][768] bf16 x
    const u16* __restrict__ Bm,      // [2304][768] bf16 qkv_w
    const float* __restrict__ bias,  // [2304]
    u16* __restrict__ qb, u16* __restrict__ kb, u16* __restrict__ vb) {
    __shared__ __align__(16) u16 As[2][256 * 64];  // 64 KB
    __shared__ __align__(16) u16 Bs[2][256 * 64];  // 64 KB
    const int tid = threadIdx.x;
    const int w = tid >> 6, l = tid & 63;
    const int wy = w >> 2, wx = w & 3;   // 2 M-waves x 4 N-waves
    const int dl = l & 15, g4 = l >> 4;
    const int fr = (dl & 7) << 4;

    // bijective XCD chunking: nwg=225, q=28, r=1
    const int wg = blockIdx.x;
    const int xcd = wg & 7, pos = wg >> 3;
    const int id2 = (xcd < 1 ? xcd * 29 : 29 + (xcd - 1) * 28) + pos;
    const int bm = id2 / 9, bn = id2 % 9;

#define STG(tau, k)                                                                          \
    if ((tau) < 12) {                                                                        \
        const u16* P = ((k) & 1) ? Bm : A;                                                   \
        const int tb = ((k) & 1) ? bn : bm;                                                  \
        char* Lb = (char*)(((k) & 1) ? Bs[(tau) & 1] : As[(tau) & 1]);                       \
        _Pragma("unroll")                                                                    \
        for (int j = 0; j < 2; ++j) {                                                        \
            int c = j * 512 + tid;                                                           \
            int row = (((k) >> 1) << 7) + (c >> 3);                                          \
            int cs = ((c & 7) << 4) ^ ((row & 7) << 4);                                      \
            __builtin_amdgcn_global_load_lds(                                                \
                GPTR((const char*)(P + (size_t)(tb * 256 + row) * 768 + (tau) * 64) + cs),   \
                LPTR(Lb + row * 128 + ((c & 7) << 4)), 16, 0, 0);                            \
        }                                                                                    \
    }

#define RD_A(qm, Tb)                                                                         \
    _Pragma("unroll")                                                                        \
    for (int mi = 0; mi < 4; ++mi)                                                           \
    _Pragma("unroll")                                                                        \
        for (int s = 0; s < 2; ++s)                                                          \
            af[mi][s] = *(const short8*)((const char*)As[(Tb)] +                             \
                ((qm) * 128 + wy * 64 + mi * 16 + dl) * 128 + (((s << 6) | (g4 << 4)) ^ fr));

#define RD_B(qn, Tb)                                                                         \
    _Pragma("unroll")                                                                        \
    for (int ni = 0; ni < 2; ++ni)                                                           \
    _Pragma("unroll")                                                                        \
        for (int s = 0; s < 2; ++s)                                                          \
            bf[ni][s] = *(const short8*)((const char*)Bs[(Tb)] +                             \
                ((qn) * 128 + wx * 32 + ni * 16 + dl) * 128 + (((s << 6) | (g4 << 4)) ^ fr));

#define MM(qm, qn)                                                                           \
    __builtin_amdgcn_s_setprio(1);                                                           \
    _Pragma("unroll")                                                                        \
    for (int s = 0; s < 2; ++s)                                                              \
    _Pragma("unroll")                                                                        \
        for (int mi = 0; mi < 4; ++mi)                                                       \
        _Pragma("unroll")                                                                    \
            for (int ni = 0; ni < 2; ++ni)                                                   \
                acc[qm][qn][mi][ni] = __builtin_amdgcn_mfma_f32_16x16x32_bf16(               \
                    af[mi][s], bf[ni][s], acc[qm][qn][mi][ni], 0, 0, 0);                     \
    __builtin_amdgcn_s_setprio(0);

#define FENCE asm volatile("" ::: "memory")
#define VM(n) asm volatile("s_waitcnt vmcnt(" #n ")" ::: "memory")
#define BAR __builtin_amdgcn_s_barrier()

    f32x4 acc[2][2][4][2] = {};
    short8 af[4][2], bf[2][2];

    // prologue: A0(0) B0(0) A1(0) B1(0) A0(1) B0(1) -> 12 loads in flight
    STG(0, 0) STG(0, 1) STG(0, 2) STG(0, 3) STG(1, 0) STG(1, 1)

#pragma unroll 1
    for (int T = 0; T < 12; ++T) {
        const int Tb = T & 1;
        if (T < 11) { VM(8); } else { VM(4); }
        BAR; FENCE;
        RD_A(0, Tb) RD_B(0, Tb)
        STG(T + 1, 2)
        MM(0, 0)
        FENCE; BAR; FENCE;
        RD_B(1, Tb)
        STG(T + 1, 3)
        MM(0, 1)
        FENCE;
        if (T < 11) { VM(8); } else { VM(0); }
        BAR; FENCE;
        RD_A(1, Tb) RD_B(0, Tb)
        STG(T + 2, 0)
        MM(1, 0)
        FENCE; BAR; FENCE;
        RD_B(1, Tb)
        STG(T + 2, 1)
        MM(1, 1)
        FENCE;
    }
#undef STG
#undef RD_A
#undef RD_B
#undef MM

    // epilogue: split into q/k/v (B,H,N,D) bf16; SCALE folded into q
#pragma unroll
    for (int qn = 0; qn < 2; ++qn)
#pragma unroll
        for (int ni = 0; ni < 2; ++ni) {
            int col = bn * 256 + qn * 128 + wx * 32 + ni * 16 + dl;
            int s = (col >= 1536) ? 2 : (col >= 768) ? 1 : 0;
            int j = col - s * 768;
            int h = j >> 6, d = j & 63;
            float bv = bias[col];
            u16* dst = (s == 0) ? qb : (s == 1) ? kb : vb;
            float sc = (s == 0) ? 0.125f : 1.0f;
#pragma unroll
            for (int qm = 0; qm < 2; ++qm)
#pragma unroll
                for (int mi = 0; mi < 4; ++mi)
#pragma unroll
                    for (int r = 0; r < 4; ++r) {
                        int row = bm * 256 + qm * 128 + wy * 64 + mi * 16 + g4 * 4 + r;
                        if (row < 6304) {
                            int bi = row / 197;
                            int n = row - bi * 197;
                            dst[((size_t)(bi * 12 + h) * 197 + n) * 64 + d] =
                                f2bf((acc[qm][qn][mi][ni][r] + bv) * sc);
                        }
                    }
        }
}

// ---------------- K2: attention, ONE block per (b,h), 8 waves, single-stage ----------------
// grid 384 x 512thr: K/V staged ONCE per head (was twice in the 768-grid half-split);
// 13 q-chunks over 8 waves (5x2 + 3x1, no idle wave-slots -- fixes R14's 768x512 idle).
#define VPAD 212
__global__ __launch_bounds__(512) void attn_kernel(
    const u16* __restrict__ qg_all, const u16* __restrict__ kg_all, const u16* __restrict__ vg_all,
    const int* __restrict__ y, const float* __restrict__ mask_attn,
    u16* __restrict__ omid) {
    __shared__ __align__(16) u16 Ks[208 * 64];    // XOR-swizzled rows
    __shared__ __align__(16) u16 Vst[64 * VPAD];  // V^T, padded rows
    const int bh = blockIdx.x;
    const int b = bh / 12, h = bh % 12;
    const int tid = threadIdx.x, w = tid >> 6, l = tid & 63;
    const int dl = l & 15, g = l >> 4;
    const size_t base = (size_t)bh * 197 * 64;
    const u16* qg = qg_all + base;
    const u16* kg = kg_all + base;
    const u16* vg = vg_all + base;
    const short8 zero8 = {0, 0, 0, 0, 0, 0, 0, 0};
    const int ycls = y[b];

    for (int c = tid; c < 208 * 8; c += 512) {  // K tile, swizzled, zero pad rows 197..207
        int row = c >> 3, colb = (c & 7) * 16;
        short8 val = zero8;
        if (row < 197) val = *(const short8*)(kg + row * 64 + (c & 7) * 8);
        int bo = (row * 128 + colb) ^ ((row & 7) << 4);
        *(short8*)((char*)Ks + bo) = val;
    }
    for (int c = tid; c < 208 * 8; c += 512) {  // V transposed, zero pad keys 197..207
        int row = c >> 3, col = (c & 7) * 8;
        short8 val = zero8;
        if (row < 197) val = *(const short8*)(vg + row * 64 + col);
#pragma unroll
        for (int j = 0; j < 8; ++j) Vst[(col + j) * VPAD + row] = (u16)val[j];
    }
    __syncthreads();

    for (int ci = w; ci < 13; ci += 8) {  // 8 waves: 5 waves x2 chunks, 3 waves x1
        int qrow = ci * 16 + dl;
        const u16* qr = qg + (size_t)qrow * 64 + g * 8;
        short8 q0 = *(const short8*)(qr);
        short8 q1 = *(const short8*)(qr + 32);

        f32x4 sc[13];
#pragma unroll
        for (int jb = 0; jb < 13; ++jb) {
            int krow = jb * 16 + dl;
            int sw = (krow & 7) << 4;
            short8 k0 = *(const short8*)((const char*)Ks + ((krow * 128 + g * 16) ^ sw));
            short8 k1 = *(const short8*)((const char*)Ks + ((krow * 128 + 64 + g * 16) ^ sw));
            f32x4 t = {0.f, 0.f, 0.f, 0.f};
            t = __builtin_amdgcn_mfma_f32_16x16x32_bf16(k0, q0, t, 0, 0, 0);
            t = __builtin_amdgcn_mfma_f32_16x16x32_bf16(k1, q1, t, 0, 0, 0);
            sc[jb] = t;
        }
#pragma unroll
        for (int r = 0; r < 4; ++r)
            if (192 + g * 4 + r >= 197) sc[12][r] = -1e30f;

        float mx = -1e30f;
#pragma unroll
        for (int jb = 0; jb < 13; ++jb)
#pragma unroll
            for (int r = 0; r < 4; ++r) mx = fmaxf(mx, sc[jb][r]);
        mx = fmaxf(mx, __shfl_xor(mx, 16));
        mx = fmaxf(mx, __shfl_xor(mx, 32));
        float ssum = 0.f;
#pragma unroll
        for (int jb = 0; jb < 13; ++jb)
#pragma unroll
            for (int r = 0; r < 4; ++r) {
                float e = __expf(sc[jb][r] - mx);
                sc[jb][r] = e;
                ssum += e;
            }
        ssum += __shfl_xor(ssum, 16);
        ssum += __shfl_xor(ssum, 32);
        float inv = 1.0f / ssum;

        s16x4 pb[13];
#pragma unroll
        for (int jb = 0; jb < 13; ++jb) {
            s16x4 pv;
#pragma unroll
            for (int r = 0; r < 4; ++r) pv[r] = (short)f2bf(sc[jb][r] * inv);
            pb[jb] = pv;
        }

        // Uniform whole-wave MFMA; only the store is per-lane predicated (R5 lesson).
#pragma unroll
        for (int db = 0; db < 4; ++db) {
            f32x4 o = {0.f, 0.f, 0.f, 0.f};
#pragma unroll
            for (int jb = 0; jb < 13; ++jb) {
                s16x4 va = *(const s16x4*)&Vst[(db * 16 + dl) * VPAD + jb * 16 + g * 4];
                o = MFMA16x16(va, pb[jb], o);
            }
            if (qrow < 197) {
                int d = db * 16 + g * 4;
                f32x4 mv = *(const f32x4*)(mask_attn + ((size_t)ycls * 12 + h) * 64 + d);
                u16x4 ov;
#pragma unroll
                for (int r = 0; r < 4; ++r) ov[r] = f2bf(o[r] * mv[r]);
                *(u16x4*)(omid + ((size_t)(b * 256 + qrow)) * 768 + h * 64 + d) = ov;
            }
        }
    }
}

// ---------------- K4: proj GEMM, 256(M=197pad) x 64(N), BK=64 (R12/R18 verbatim) ----------------
__global__ __launch_bounds__(512, 4) void proj_gemm_kernel(
    const u16* __restrict__ A,          // omid [32][256][768] bf16
    const float* __restrict__ proj_w,   // [768][768] f32
    const float* __restrict__ mask_proj,// [100][768][768] f32
    const int* __restrict__ y,
    const float* __restrict__ bias,     // [768]
    float* __restrict__ out) {          // [32][197][768] f32
    __shared__ __align__(16) u16 Ap[2][256 * 64];  // 64 KB
    __shared__ __align__(16) u16 Bp[2][64 * 64];   // 16 KB
    const int tid = threadIdx.x;
    const int w = tid >> 6, l = tid & 63;
    const int wy = w >> 1, wx = w & 1;   // 4 M-waves x 2 N-waves (64x32 each)
    const int dl = l & 15, g4 = l >> 4;
    const int fr = (dl & 7) << 4;

    // bijective XCD chunking: nwg=384, q=48, r=0; bn-fast -> omid panel L2 reuse
    const int wg = blockIdx.x;
    const int id2 = (wg & 7) * 48 + (wg >> 3);
    const int b = id2 / 12, bn = id2 % 12;
    const size_t mbase = (size_t)y[b] * 589824;

    const int brow = tid >> 3;           // B-stage: N-row 0..63
    const int bcolf = (tid & 7) * 8;     // 8 f32 K-cols per thread
    const int bcb = bcolf * 2;           // byte col in bf16 LDS row
    const int bsw = (brow & 7) << 4;

    f32x4 pw[2], pm[2];

#define PROJ_LOADB(kt)                                                              \
    {                                                                               \
        size_t off = (size_t)(bn * 64 + brow) * 768 + (kt) + bcolf;                 \
        pw[0] = *(const f32x4*)(proj_w + off);                                      \
        pw[1] = *(const f32x4*)(proj_w + off + 4);                                  \
        pm[0] = *(const f32x4*)(mask_proj + mbase + off);                           \
        pm[1] = *(const f32x4*)(mask_proj + mbase + off + 4);                       \
    }

#define PROJ_WRITEB(bi)                                                             \
    {                                                                               \
        short8 o0;                                                                  \
        _Pragma("unroll")                                                           \
        for (int j = 0; j < 4; ++j) {                                               \
            o0[j] = (short)f2bf(pw[0][j] * pm[0][j]);                               \
            o0[4 + j] = (short)f2bf(pw[1][j] * pm[1][j]);                           \
        }                                                                           \
        *(short8*)((char*)Bp[bi] + brow * 128 + (bcb ^ bsw)) = o0;                  \
    }

#define PROJ_STAGEA(bi, kt)                                                         \
    {                                                                               \
        _Pragma("unroll")                                                           \
        for (int cc = 0; cc < 4; ++cc) {                                            \
            int c = w * 256 + cc * 64 + l;                                          \
            int row = c >> 3;                                                       \
            int cs = ((c & 7) << 4) ^ ((row & 7) << 4);                             \
            __builtin_amdgcn_global_load_lds(                                       \
                GPTR((const char*)(A + (size_t)(b * 256 + row) * 768 + (kt)) + cs), \
                LPTR((char*)Ap[bi] + c * 16), 16, 0, 0);                            \
        }                                                                           \
    }

    f32x4 acc[4][2] = {};
    PROJ_LOADB(0)
    PROJ_STAGEA(0, 0)
    PROJ_WRITEB(0)
    __syncthreads();
    int cur = 0;
#pragma unroll 1
    for (int t = 0; t < 12; ++t) {
        if (t < 11) {
            PROJ_STAGEA(cur ^ 1, (t + 1) * 64)  // async A prefetch
            PROJ_LOADB((t + 1) * 64)            // B f32 loads issue early...
        }
#pragma unroll
        for (int s = 0; s < 2; ++s) {
            const int ce = ((s << 6) | (g4 << 4)) ^ fr;
            short8 af[4], bf[2];
#pragma unroll
            for (int mi = 0; mi < 4; ++mi)
                af[mi] = *(const short8*)((const char*)Ap[cur] + (wy * 64 + mi * 16 + dl) * 128 + ce);
#pragma unroll
            for (int ni = 0; ni < 2; ++ni)
                bf[ni] = *(const short8*)((const char*)Bp[cur] + (wx * 32 + ni * 16 + dl) * 128 + ce);
#pragma unroll
            for (int mi = 0; mi < 4; ++mi)
#pragma unroll
                for (int ni = 0; ni < 2; ++ni)
                    acc[mi][ni] = __builtin_amdgcn_mfma_f32_16x16x32_bf16(af[mi], bf[ni], acc[mi][ni], 0, 0, 0);
        }
        if (t < 11) PROJ_WRITEB(cur ^ 1)        // ...convert+write late (latency hidden)
        __syncthreads();
        cur ^= 1;
    }

#pragma unroll
    for (int ni = 0; ni < 2; ++ni) {
        int col = bn * 64 + wx * 32 + ni * 16 + dl;
        float bv = bias[col];
#pragma unroll
        for (int mi = 0; mi < 4; ++mi) {
#pragma unroll
            for (int r = 0; r < 4; ++r) {
                int row = wy * 64 + mi * 16 + g4 * 4 + r;
                if (row < 197)
                    out[((size_t)b * 197 + row) * 768 + col] = acc[mi][ni][r] + bv;
            }
        }
    }
#undef PROJ_LOADB
#undef PROJ_WRITEB
#undef PROJ_STAGEA
}

extern "C" void kernel_launch(void* const* d_in, const int* in_sizes, int n_in,
                              void* d_out, int out_size, void* d_ws, size_t ws_size,
                              hipStream_t stream) {
    const float* x = (const float*)d_in[0];
    const int* y = (const int*)d_in[1];
    const float* qkv_w = (const float*)d_in[2];
    const float* qkv_b = (const float*)d_in[3];
    const float* proj_w = (const float*)d_in[4];
    const float* proj_b = (const float*)d_in[5];
    const float* mask_attn = (const float*)d_in[6];
    const float* mask_proj = (const float*)d_in[7];
    float* out = (float*)d_out;

    // workspace layout (bf16 = u16), ~55.3 MB
    u16* xb = (u16*)d_ws;                       // [6400][768]
    u16* wqkvb = xb + (size_t)6400 * 768;       // [2304][768]
    u16* qb = wqkvb + (size_t)2304 * 768;       // [76288][64]
    u16* kb = qb + (size_t)76288 * 64;
    u16* vb = kb + (size_t)76288 * 64;
    u16* omid = vb + (size_t)76288 * 64;        // [32][256][768]

    cvt_fused_kernel<<<6456, 256, 0, stream>>>(x, qkv_w, xb, wqkvb);
    qkv_gemm_kernel<<<225, 512, 0, stream>>>(xb, wqkvb, qkv_b, qb, kb, vb);
    attn_kernel<<<384, 512, 0, stream>>>(qb, kb, vb, y, mask_attn, omid);
    proj_gemm_kernel<<<384, 512, 0, stream>>>(omid, proj_w, mask_proj, y, proj_b, out);
}

// Round 20
// 116.699 us; speedup vs baseline: 1.7369x; 1.0037x over previous
//
#include <hip/hip_runtime.h>

typedef unsigned short u16;
typedef __attribute__((ext_vector_type(8))) short short8;
typedef __attribute__((ext_vector_type(4))) short s16x4;
typedef __attribute__((ext_vector_type(4))) float f32x4;
typedef __attribute__((ext_vector_type(4))) u16 u16x4;

#define GPTR(p) ((const __attribute__((address_space(1))) void*)(p))
#define LPTR(p) ((__attribute__((address_space(3))) void*)(p))

#if __has_builtin(__builtin_amdgcn_mfma_f32_16x16x16bf16_1k)
#define MFMA16x16(a, b, c) __builtin_amdgcn_mfma_f32_16x16x16bf16_1k(a, b, c, 0, 0, 0)
#elif __has_builtin(__builtin_amdgcn_mfma_f32_16x16x16_bf16)
#define MFMA16x16(a, b, c) __builtin_amdgcn_mfma_f32_16x16x16_bf16(a, b, c, 0, 0, 0)
#else
__host__ __device__ static inline f32x4 MFMA16x16_host_stub(s16x4, s16x4, f32x4 c) { return c; }
#define MFMA16x16(a, b, c) MFMA16x16_host_stub(a, b, c)
#endif

__device__ __forceinline__ u16 f2bf(float f) {
    union { float f; unsigned u; } a; a.f = f;
    unsigned r = a.u + 0x7FFFu + ((a.u >> 16) & 1u);  // RNE
    return (u16)(r >> 16);
}

// ---------------- K0: fused f32 -> bf16 convert (x then qkv_w) ----------------
__global__ __launch_bounds__(256) void cvt_fused_kernel(const float* __restrict__ xin,
                                                        const float* __restrict__ win,
                                                        u16* __restrict__ xout,
                                                        u16* __restrict__ wout) {
    int i = (blockIdx.x * 256 + threadIdx.x) * 4;
    const float* src;
    u16* dst;
    int j;
    if (i < 4841472) {
        src = xin; dst = xout; j = i;
    } else {
        src = win; dst = wout; j = i - 4841472;
    }
    f32x4 v = *(const f32x4*)(src + j);
    u16x4 o;
#pragma unroll
    for (int k = 0; k < 4; ++k) o[k] = f2bf(v[k]);
    *(u16x4*)(dst + j) = o;
}

// ---------------- K1: QKV GEMM 6400x2304x768 — 8-phase schedule (R15/R18 verbatim) ----------------
__global__ __launch_bounds__(512, 2) void qkv_gemm_kernel(
    const u16* __restrict__ A,       // [6400][768] bf16 x
    const u16* __restrict__ Bm,      // [2304][768] bf16 qkv_w
    const float* __restrict__ bias,  // [2304]
    u16* __restrict__ qb, u16* __restrict__ kb, u16* __restrict__ vb) {
    __shared__ __align__(16) u16 As[2][256 * 64];  // 64 KB
    __shared__ __align__(16) u16 Bs[2][256 * 64];  // 64 KB
    const int tid = threadIdx.x;
    const int w = tid >> 6, l = tid & 63;
    const int wy = w >> 2, wx = w & 3;   // 2 M-waves x 4 N-waves
    const int dl = l & 15, g4 = l >> 4;
    const int fr = (dl & 7) << 4;

    // bijective XCD chunking: nwg=225, q=28, r=1
    const int wg = blockIdx.x;
    const int xcd = wg & 7, pos = wg >> 3;
    const int id2 = (xcd < 1 ? xcd * 29 : 29 + (xcd - 1) * 28) + pos;
    const int bm = id2 / 9, bn = id2 % 9;

#define STG(tau, k)                                                                          \
    if ((tau) < 12) {                                                                        \
        const u16* P = ((k) & 1) ? Bm : A;                                                   \
        const int tb = ((k) & 1) ? bn : bm;                                                  \
        char* Lb = (char*)(((k) & 1) ? Bs[(tau) & 1] : As[(tau) & 1]);                       \
        _Pragma("unroll")                                                                    \
        for (int j = 0; j < 2; ++j) {                                                        \
            int c = j * 512 + tid;                                                           \
            int row = (((k) >> 1) << 7) + (c >> 3);                                          \
            int cs = ((c & 7) << 4) ^ ((row & 7) << 4);                                      \
            __builtin_amdgcn_global_load_lds(                                                \
                GPTR((const char*)(P + (size_t)(tb * 256 + row) * 768 + (tau) * 64) + cs),   \
                LPTR(Lb + row * 128 + ((c & 7) << 4)), 16, 0, 0);                            \
        }                                                                                    \
    }

#define RD_A(qm, Tb)                                                                         \
    _Pragma("unroll")                                                                        \
    for (int mi = 0; mi < 4; ++mi)                                                           \
    _Pragma("unroll")                                                                        \
        for (int s = 0; s < 2; ++s)                                                          \
            af[mi][s] = *(const short8*)((const char*)As[(Tb)] +                             \
                ((qm) * 128 + wy * 64 + mi * 16 + dl) * 128 + (((s << 6) | (g4 << 4)) ^ fr));

#define RD_B(qn, Tb)                                                                         \
    _Pragma("unroll")                                                                        \
    for (int ni = 0; ni < 2; ++ni)                                                           \
    _Pragma("unroll")                                                                        \
        for (int s = 0; s < 2; ++s)                                                          \
            bf[ni][s] = *(const short8*)((const char*)Bs[(Tb)] +                             \
                ((qn) * 128 + wx * 32 + ni * 16 + dl) * 128 + (((s << 6) | (g4 << 4)) ^ fr));

#define MM(qm, qn)                                                                           \
    __builtin_amdgcn_s_setprio(1);                                                           \
    _Pragma("unroll")                                                                        \
    for (int s = 0; s < 2; ++s)                                                              \
    _Pragma("unroll")                                                                        \
        for (int mi = 0; mi < 4; ++mi)                                                       \
        _Pragma("unroll")                                                                    \
            for (int ni = 0; ni < 2; ++ni)                                                   \
                acc[qm][qn][mi][ni] = __builtin_amdgcn_mfma_f32_16x16x32_bf16(               \
                    af[mi][s], bf[ni][s], acc[qm][qn][mi][ni], 0, 0, 0);                     \
    __builtin_amdgcn_s_setprio(0);

#define FENCE asm volatile("" ::: "memory")
#define VM(n) asm volatile("s_waitcnt vmcnt(" #n ")" ::: "memory")
#define BAR __builtin_amdgcn_s_barrier()

    f32x4 acc[2][2][4][2] = {};
    short8 af[4][2], bf[2][2];

    // prologue: A0(0) B0(0) A1(0) B1(0) A0(1) B0(1) -> 12 loads in flight
    STG(0, 0) STG(0, 1) STG(0, 2) STG(0, 3) STG(1, 0) STG(1, 1)

#pragma unroll 1
    for (int T = 0; T < 12; ++T) {
        const int Tb = T & 1;
        if (T < 11) { VM(8); } else { VM(4); }
        BAR; FENCE;
        RD_A(0, Tb) RD_B(0, Tb)
        STG(T + 1, 2)
        MM(0, 0)
        FENCE; BAR; FENCE;
        RD_B(1, Tb)
        STG(T + 1, 3)
        MM(0, 1)
        FENCE;
        if (T < 11) { VM(8); } else { VM(0); }
        BAR; FENCE;
        RD_A(1, Tb) RD_B(0, Tb)
        STG(T + 2, 0)
        MM(1, 0)
        FENCE; BAR; FENCE;
        RD_B(1, Tb)
        STG(T + 2, 1)
        MM(1, 1)
        FENCE;
    }
#undef STG
#undef RD_A
#undef RD_B
#undef MM

    // epilogue: split into q/k/v (B,H,N,D) bf16; SCALE folded into q
#pragma unroll
    for (int qn = 0; qn < 2; ++qn)
#pragma unroll
        for (int ni = 0; ni < 2; ++ni) {
            int col = bn * 256 + qn * 128 + wx * 32 + ni * 16 + dl;
            int s = (col >= 1536) ? 2 : (col >= 768) ? 1 : 0;
            int j = col - s * 768;
            int h = j >> 6, d = j & 63;
            float bv = bias[col];
            u16* dst = (s == 0) ? qb : (s == 1) ? kb : vb;
            float sc = (s == 0) ? 0.125f : 1.0f;
#pragma unroll
            for (int qm = 0; qm < 2; ++qm)
#pragma unroll
                for (int mi = 0; mi < 4; ++mi)
#pragma unroll
                    for (int r = 0; r < 4; ++r) {
                        int row = bm * 256 + qm * 128 + wy * 64 + mi * 16 + g4 * 4 + r;
                        if (row < 6304) {
                            int bi = row / 197;
                            int n = row - bi * 197;
                            dst[((size_t)(bi * 12 + h) * 197 + n) * 64 + d] =
                                f2bf((acc[qm][qn][mi][ni][r] + bv) * sc);
                        }
                    }
        }
}

// ---------------- K2: attention, ONE block per (b,h), 8 waves, single-stage ----------------
// Defer-normalization: P = exp(s-mx) unnormalized (in [0,1], bf16-safe); the
// per-row 1/sum is a PER-LANE scalar in the PV output fragment (output col q = dl),
// so it folds into the existing o*mv multiply -- 52 mults/chunk saved off the
// softmax->PV critical path.
#define VPAD 212
__global__ __launch_bounds__(512) void attn_kernel(
    const u16* __restrict__ qg_all, const u16* __restrict__ kg_all, const u16* __restrict__ vg_all,
    const int* __restrict__ y, const float* __restrict__ mask_attn,
    u16* __restrict__ omid) {
    __shared__ __align__(16) u16 Ks[208 * 64];    // XOR-swizzled rows
    __shared__ __align__(16) u16 Vst[64 * VPAD];  // V^T, padded rows
    const int bh = blockIdx.x;
    const int b = bh / 12, h = bh % 12;
    const int tid = threadIdx.x, w = tid >> 6, l = tid & 63;
    const int dl = l & 15, g = l >> 4;
    const size_t base = (size_t)bh * 197 * 64;
    const u16* qg = qg_all + base;
    const u16* kg = kg_all + base;
    const u16* vg = vg_all + base;
    const short8 zero8 = {0, 0, 0, 0, 0, 0, 0, 0};
    const int ycls = y[b];

    for (int c = tid; c < 208 * 8; c += 512) {  // K tile, swizzled, zero pad rows 197..207
        int row = c >> 3, colb = (c & 7) * 16;
        short8 val = zero8;
        if (row < 197) val = *(const short8*)(kg + row * 64 + (c & 7) * 8);
        int bo = (row * 128 + colb) ^ ((row & 7) << 4);
        *(short8*)((char*)Ks + bo) = val;
    }
    for (int c = tid; c < 208 * 8; c += 512) {  // V transposed, zero pad keys 197..207
        int row = c >> 3, col = (c & 7) * 8;
        short8 val = zero8;
        if (row < 197) val = *(const short8*)(vg + row * 64 + col);
#pragma unroll
        for (int j = 0; j < 8; ++j) Vst[(col + j) * VPAD + row] = (u16)val[j];
    }
    __syncthreads();

    for (int ci = w; ci < 13; ci += 8) {  // 8 waves: 5 waves x2 chunks, 3 waves x1
        int qrow = ci * 16 + dl;
        const u16* qr = qg + (size_t)qrow * 64 + g * 8;
        short8 q0 = *(const short8*)(qr);
        short8 q1 = *(const short8*)(qr + 32);

        f32x4 sc[13];
#pragma unroll
        for (int jb = 0; jb < 13; ++jb) {
            int krow = jb * 16 + dl;
            int sw = (krow & 7) << 4;
            short8 k0 = *(const short8*)((const char*)Ks + ((krow * 128 + g * 16) ^ sw));
            short8 k1 = *(const short8*)((const char*)Ks + ((krow * 128 + 64 + g * 16) ^ sw));
            f32x4 t = {0.f, 0.f, 0.f, 0.f};
            t = __builtin_amdgcn_mfma_f32_16x16x32_bf16(k0, q0, t, 0, 0, 0);
            t = __builtin_amdgcn_mfma_f32_16x16x32_bf16(k1, q1, t, 0, 0, 0);
            sc[jb] = t;
        }
#pragma unroll
        for (int r = 0; r < 4; ++r)
            if (192 + g * 4 + r >= 197) sc[12][r] = -1e30f;

        float mx = -1e30f;
#pragma unroll
        for (int jb = 0; jb < 13; ++jb)
#pragma unroll
            for (int r = 0; r < 4; ++r) mx = fmaxf(mx, sc[jb][r]);
        mx = fmaxf(mx, __shfl_xor(mx, 16));
        mx = fmaxf(mx, __shfl_xor(mx, 32));
        float ssum = 0.f;
#pragma unroll
        for (int jb = 0; jb < 13; ++jb)
#pragma unroll
            for (int r = 0; r < 4; ++r) {
                float e = __expf(sc[jb][r] - mx);
                sc[jb][r] = e;
                ssum += e;
            }
        ssum += __shfl_xor(ssum, 16);
        ssum += __shfl_xor(ssum, 32);
        float inv = 1.0f / ssum;

        s16x4 pb[13];  // UNNORMALIZED P (exp values in [0,1])
#pragma unroll
        for (int jb = 0; jb < 13; ++jb) {
            s16x4 pv;
#pragma unroll
            for (int r = 0; r < 4; ++r) pv[r] = (short)f2bf(sc[jb][r]);
            pb[jb] = pv;
        }

        // Uniform whole-wave MFMA; only the store is per-lane predicated (R5 lesson).
        // inv is per-lane (output col q = dl) -> folded into the mask multiply.
#pragma unroll
        for (int db = 0; db < 4; ++db) {
            f32x4 o = {0.f, 0.f, 0.f, 0.f};
#pragma unroll
            for (int jb = 0; jb < 13; ++jb) {
                s16x4 va = *(const s16x4*)&Vst[(db * 16 + dl) * VPAD + jb * 16 + g * 4];
                o = MFMA16x16(va, pb[jb], o);
            }
            if (qrow < 197) {
                int d = db * 16 + g * 4;
                f32x4 mv = *(const f32x4*)(mask_attn + ((size_t)ycls * 12 + h) * 64 + d);
                u16x4 ov;
#pragma unroll
                for (int r = 0; r < 4; ++r) ov[r] = f2bf(o[r] * inv * mv[r]);
                *(u16x4*)(omid + ((size_t)(b * 256 + qrow)) * 768 + h * 64 + d) = ov;
            }
        }
    }
}

// ---------------- K4: proj GEMM, 256(M=197pad) x 64(N), BK=64 (R12/R18 verbatim) ----------------
__global__ __launch_bounds__(512, 4) void proj_gemm_kernel(
    const u16* __restrict__ A,          // omid [32][256][768] bf16
    const float* __restrict__ proj_w,   // [768][768] f32
    const float* __restrict__ mask_proj,// [100][768][768] f32
    const int* __restrict__ y,
    const float* __restrict__ bias,     // [768]
    float* __restrict__ out) {          // [32][197][768] f32
    __shared__ __align__(16) u16 Ap[2][256 * 64];  // 64 KB
    __shared__ __align__(16) u16 Bp[2][64 * 64];   // 16 KB
    const int tid = threadIdx.x;
    const int w = tid >> 6, l = tid & 63;
    const int wy = w >> 1, wx = w & 1;   // 4 M-waves x 2 N-waves (64x32 each)
    const int dl = l & 15, g4 = l >> 4;
    const int fr = (dl & 7) << 4;

    // bijective XCD chunking: nwg=384, q=48, r=0; bn-fast -> omid panel L2 reuse
    const int wg = blockIdx.x;
    const int id2 = (wg & 7) * 48 + (wg >> 3);
    const int b = id2 / 12, bn = id2 % 12;
    const size_t mbase = (size_t)y[b] * 589824;

    const int brow = tid >> 3;           // B-stage: N-row 0..63
    const int bcolf = (tid & 7) * 8;     // 8 f32 K-cols per thread
    const int bcb = bcolf * 2;           // byte col in bf16 LDS row
    const int bsw = (brow & 7) << 4;

    f32x4 pw[2], pm[2];

#define PROJ_LOADB(kt)                                                              \
    {                                                                               \
        size_t off = (size_t)(bn * 64 + brow) * 768 + (kt) + bcolf;                 \
        pw[0] = *(const f32x4*)(proj_w + off);                                      \
        pw[1] = *(const f32x4*)(proj_w + off + 4);                                  \
        pm[0] = *(const f32x4*)(mask_proj + mbase + off);                           \
        pm[1] = *(const f32x4*)(mask_proj + mbase + off + 4);                       \
    }

#define PROJ_WRITEB(bi)                                                             \
    {                                                                               \
        short8 o0;                                                                  \
        _Pragma("unroll")                                                           \
        for (int j = 0; j < 4; ++j) {                                               \
            o0[j] = (short)f2bf(pw[0][j] * pm[0][j]);                               \
            o0[4 + j] = (short)f2bf(pw[1][j] * pm[1][j]);                           \
        }                                                                           \
        *(short8*)((char*)Bp[bi] + brow * 128 + (bcb ^ bsw)) = o0;                  \
    }

#define PROJ_STAGEA(bi, kt)                                                         \
    {                                                                               \
        _Pragma("unroll")                                                           \
        for (int cc = 0; cc < 4; ++cc) {                                            \
            int c = w * 256 + cc * 64 + l;                                          \
            int row = c >> 3;                                                       \
            int cs = ((c & 7) << 4) ^ ((row & 7) << 4);                             \
            __builtin_amdgcn_global_load_lds(                                       \
                GPTR((const char*)(A + (size_t)(b * 256 + row) * 768 + (kt)) + cs), \
                LPTR((char*)Ap[bi] + c * 16), 16, 0, 0);                            \
        }                                                                           \
    }

    f32x4 acc[4][2] = {};
    PROJ_LOADB(0)
    PROJ_STAGEA(0, 0)
    PROJ_WRITEB(0)
    __syncthreads();
    int cur = 0;
#pragma unroll 1
    for (int t = 0; t < 12; ++t) {
        if (t < 11) {
            PROJ_STAGEA(cur ^ 1, (t + 1) * 64)  // async A prefetch
            PROJ_LOADB((t + 1) * 64)            // B f32 loads issue early...
        }
#pragma unroll
        for (int s = 0; s < 2; ++s) {
            const int ce = ((s << 6) | (g4 << 4)) ^ fr;
            short8 af[4], bf[2];
#pragma unroll
            for (int mi = 0; mi < 4; ++mi)
                af[mi] = *(const short8*)((const char*)Ap[cur] + (wy * 64 + mi * 16 + dl) * 128 + ce);
#pragma unroll
            for (int ni = 0; ni < 2; ++ni)
                bf[ni] = *(const short8*)((const char*)Bp[cur] + (wx * 32 + ni * 16 + dl) * 128 + ce);
#pragma unroll
            for (int mi = 0; mi < 4; ++mi)
#pragma unroll
                for (int ni = 0; ni < 2; ++ni)
                    acc[mi][ni] = __builtin_amdgcn_mfma_f32_16x16x32_bf16(af[mi], bf[ni], acc[mi][ni], 0, 0, 0);
        }
        if (t < 11) PROJ_WRITEB(cur ^ 1)        // ...convert+write late (latency hidden)
        __syncthreads();
        cur ^= 1;
    }

#pragma unroll
    for (int ni = 0; ni < 2; ++ni) {
        int col = bn * 64 + wx * 32 + ni * 16 + dl;
        float bv = bias[col];
#pragma unroll
        for (int mi = 0; mi < 4; ++mi) {
#pragma unroll
            for (int r = 0; r < 4; ++r) {
                int row = wy * 64 + mi * 16 + g4 * 4 + r;
                if (row < 197)
                    out[((size_t)b * 197 + row) * 768 + col] = acc[mi][ni][r] + bv;
            }
        }
    }
#undef PROJ_LOADB
#undef PROJ_WRITEB
#undef PROJ_STAGEA
}

extern "C" void kernel_launch(void* const* d_in, const int* in_sizes, int n_in,
                              void* d_out, int out_size, void* d_ws, size_t ws_size,
                              hipStream_t stream) {
    const float* x = (const float*)d_in[0];
    const int* y = (const int*)d_in[1];
    const float* qkv_w = (const float*)d_in[2];
    const float* qkv_b = (const float*)d_in[3];
    const float* proj_w = (const float*)d_in[4];
    const float* proj_b = (const float*)d_in[5];
    const float* mask_attn = (const float*)d_in[6];
    const float* mask_proj = (const float*)d_in[7];
    float* out = (float*)d_out;

    // workspace layout (bf16 = u16), ~55.3 MB
    u16* xb = (u16*)d_ws;                       // [6400][768]
    u16* wqkvb = xb + (size_t)6400 * 768;       // [2304][768]
    u16* qb = wqkvb + (size_t)2304 * 768;       // [76288][64]
    u16* kb = qb + (size_t)76288 * 64;
    u16* vb = kb + (size_t)76288 * 64;
    u16* omid = vb + (size_t)76288 * 64;        // [32][256][768]

    cvt_fused_kernel<<<6456, 256, 0, stream>>>(x, qkv_w, xb, wqkvb);
    qkv_gemm_kernel<<<225, 512, 0, stream>>>(xb, wqkvb, qkv_b, qb, kb, vb);
    attn_kernel<<<384, 512, 0, stream>>>(qb, kb, vb, y, mask_attn, omid);
    proj_gemm_kernel<<<384, 512, 0, stream>>>(omid, proj_w, mask_proj, y, proj_b, out);
}